// Round 1
// baseline (4937.251 us; speedup 1.0000x reference)
//
#include <hip/hip_runtime.h>
#include <cstdio>

#define N_TOK 16384
#define CDIM  512

// ---------------------------------------------------------------- zero
__global__ void zero_kernel(float* __restrict__ p, int n) {
  int i = blockIdx.x * blockDim.x + threadIdx.x;
  if (i < n) p[i] = 0.f;
}

// ---------------------------------------------------------------- GEMM
// C[M x Nout] = A[M x K] * B[Nout x K]^T + bias   (all row-major, lda=ldb=K)
// grid = (M/128, Nout/128), block = 256. BM=BN=128, BK=16, 8x8 per thread.
__global__ __launch_bounds__(256) void gemm_nt(const float* __restrict__ A,
                                               const float* __restrict__ B,
                                               const float* __restrict__ bias,
                                               float* __restrict__ C,
                                               int K, int ldc) {
  __shared__ float As[16][132];
  __shared__ float Bs[16][132];
  const int t = threadIdx.x;
  const size_t bm = (size_t)blockIdx.x * 128;
  const size_t bn = (size_t)blockIdx.y * 128;
  const int arow = t >> 2;          // 0..63
  const int ak4  = (t & 3) * 4;     // 0,4,8,12
  const int tr   = (t >> 4) * 8;    // 0..120
  const int tc   = (t & 15) * 8;    // 0..120
  float acc[8][8] = {};
  const float* Ab = A + (bm + arow) * (size_t)K + ak4;
  const float* Bb = B + (bn + arow) * (size_t)K + ak4;
  for (int k0 = 0; k0 < K; k0 += 16) {
    float4 av0 = *(const float4*)(Ab + k0);
    float4 av1 = *(const float4*)(Ab + (size_t)64 * K + k0);
    float4 bv0 = *(const float4*)(Bb + k0);
    float4 bv1 = *(const float4*)(Bb + (size_t)64 * K + k0);
    __syncthreads();
    As[ak4+0][arow]    = av0.x; As[ak4+1][arow]    = av0.y;
    As[ak4+2][arow]    = av0.z; As[ak4+3][arow]    = av0.w;
    As[ak4+0][arow+64] = av1.x; As[ak4+1][arow+64] = av1.y;
    As[ak4+2][arow+64] = av1.z; As[ak4+3][arow+64] = av1.w;
    Bs[ak4+0][arow]    = bv0.x; Bs[ak4+1][arow]    = bv0.y;
    Bs[ak4+2][arow]    = bv0.z; Bs[ak4+3][arow]    = bv0.w;
    Bs[ak4+0][arow+64] = bv1.x; Bs[ak4+1][arow+64] = bv1.y;
    Bs[ak4+2][arow+64] = bv1.z; Bs[ak4+3][arow+64] = bv1.w;
    __syncthreads();
#pragma unroll
    for (int kk = 0; kk < 16; ++kk) {
      float a[8], b[8];
      *(float4*)&a[0] = *(const float4*)&As[kk][tr];
      *(float4*)&a[4] = *(const float4*)&As[kk][tr + 4];
      *(float4*)&b[0] = *(const float4*)&Bs[kk][tc];
      *(float4*)&b[4] = *(const float4*)&Bs[kk][tc + 4];
#pragma unroll
      for (int i = 0; i < 8; ++i)
#pragma unroll
        for (int j = 0; j < 8; ++j)
          acc[i][j] = fmaf(a[i], b[j], acc[i][j]);
    }
  }
#pragma unroll
  for (int i = 0; i < 8; ++i) {
    float o[8];
#pragma unroll
    for (int j = 0; j < 8; ++j) o[j] = acc[i][j] + bias[bn + tc + j];
    float* Cr = C + (bm + tr + i) * (size_t)ldc + bn + tc;
    *(float4*)&Cr[0] = *(float4*)&o[0];
    *(float4*)&Cr[4] = *(float4*)&o[4];
  }
}

// ---------------------------------------------------------------- nonlinearity
// In-place on q rows (ld 512) and k rows (cols 0..511 of kv, ld 1024).
// q = (relu(q)+1e-6)/softplus(scale); qn = ||row||; p = q^f; q = p * qn/||p||
__global__ __launch_bounds__(256) void nonlin_kernel(float* __restrict__ q,
                                                     float* __restrict__ kv,
                                                     const float* __restrict__ scale,
                                                     const float* __restrict__ ff) {
  __shared__ float red[8];
  const int row = blockIdx.x;
  const int t = threadIdx.x;
  const int wid = t >> 6, lane = t & 63;
  float* qr = q + (size_t)row * 512;
  float* kr = kv + (size_t)row * 1024;

  float sc0 = scale[t], sc1 = scale[t + 256];
  float s0 = (sc0 > 20.f) ? sc0 : log1pf(expf(sc0));
  float s1 = (sc1 > 20.f) ? sc1 : log1pf(expf(sc1));
  float f0 = ff[t], f1 = ff[t + 256];

  float q0 = (fmaxf(qr[t], 0.f) + 1e-6f) / s0;
  float q1 = (fmaxf(qr[t + 256], 0.f) + 1e-6f) / s1;
  float k0 = (fmaxf(kr[t], 0.f) + 1e-6f) / s0;
  float k1 = (fmaxf(kr[t + 256], 0.f) + 1e-6f) / s1;

  // reduction 1: ||q||^2, ||k||^2
  float sq = q0 * q0 + q1 * q1;
  float sk = k0 * k0 + k1 * k1;
  for (int off = 32; off > 0; off >>= 1) {
    sq += __shfl_down(sq, off);
    sk += __shfl_down(sk, off);
  }
  if (lane == 0) { red[wid * 2] = sq; red[wid * 2 + 1] = sk; }
  __syncthreads();
  float qn = sqrtf(red[0] + red[2] + red[4] + red[6]);
  float kn = sqrtf(red[1] + red[3] + red[5] + red[7]);
  __syncthreads();

  float pq0 = powf(q0, f0), pq1 = powf(q1, f1);
  float pk0 = powf(k0, f0), pk1 = powf(k1, f1);

  // reduction 2: ||q^f||^2, ||k^f||^2
  float sq2 = pq0 * pq0 + pq1 * pq1;
  float sk2 = pk0 * pk0 + pk1 * pk1;
  for (int off = 32; off > 0; off >>= 1) {
    sq2 += __shfl_down(sq2, off);
    sk2 += __shfl_down(sk2, off);
  }
  if (lane == 0) { red[wid * 2] = sq2; red[wid * 2 + 1] = sk2; }
  __syncthreads();
  float pqn = sqrtf(red[0] + red[2] + red[4] + red[6]);
  float pkn = sqrtf(red[1] + red[3] + red[5] + red[7]);

  float qs = qn / pqn, ks = kn / pkn;
  qr[t] = pq0 * qs;
  qr[t + 256] = pq1 * qs;
  kr[t] = pk0 * ks;
  kr[t + 256] = pk1 * ks;
}

// ---------------------------------------------------------------- k sum over N
// grid = (32, B); each block sums 512 rows for all 512 channels, atomicAdd.
__global__ __launch_bounds__(256) void kmean_kernel(const float* __restrict__ kv,
                                                    float* __restrict__ ksum) {
  const int b = blockIdx.y, ch = blockIdx.x, t = threadIdx.x;
  size_t base = ((size_t)b * N_TOK + (size_t)ch * 512) * 1024;
  float a0 = 0.f, a1 = 0.f;
  for (int i = 0; i < 512; ++i) {
    const float* r = kv + base + (size_t)i * 1024;
    a0 += r[t];
    a1 += r[t + 256];
  }
  atomicAdd(&ksum[b * 512 + t], a0);
  atomicAdd(&ksum[b * 512 + t + 256], a1);
}

// ---------------------------------------------------------------- z = 1/(q . k_mean + eps)
// one wave per row; lane = (head, 8-chunk)
__global__ __launch_bounds__(256) void z_kernel(const float* __restrict__ q,
                                                const float* __restrict__ ksum,
                                                float* __restrict__ z) {
  const int t = threadIdx.x;
  const int w = t >> 6, lane = t & 63;
  const int row = blockIdx.x * 4 + w;
  const int b = row >> 14, n = row & (N_TOK - 1);
  const int hh = lane >> 3, j = lane & 7;
  const float* qr = q + (size_t)row * 512 + hh * 64 + j * 8;
  const float* kr = ksum + b * 512 + hh * 64 + j * 8;
  float p = 0.f;
#pragma unroll
  for (int i = 0; i < 8; ++i) p += qr[i] * kr[i];
  p += __shfl_xor(p, 1);
  p += __shfl_xor(p, 2);
  p += __shfl_xor(p, 4);
  if (j == 0) {
    float dot = p * (1.0f / (float)N_TOK);  // ksum -> mean
    z[((size_t)(b * 8 + hh)) * N_TOK + n] = 1.0f / (dot + 1e-6f);
  }
}

// ---------------------------------------------------------------- kv_mat[bh] = k^T v / N
// grid = (32 chunks, 32 bh); block 256, 4x4 accum of the 64x64 tile, atomicAdd.
__global__ __launch_bounds__(256) void kvmat_kernel(const float* __restrict__ kv,
                                                    float* __restrict__ kvm) {
  __shared__ float ks[8][64];
  __shared__ float vs[8][64];
  const int bh = blockIdx.y;
  const int b = bh >> 3, h = bh & 7;
  const int chunk = blockIdx.x;
  const int t = threadIdx.x;
  const int tr = (t >> 4) * 4, tc = (t & 15) * 4;
  float acc[4][4] = {};
  size_t rowbase = (size_t)b * N_TOK + (size_t)chunk * 512;
  for (int it = 0; it < 64; ++it) {
    __syncthreads();
#pragma unroll
    for (int l = 0; l < 4; ++l) {
      int idx = l * 256 + t;
      int ri = idx >> 7, ci = idx & 127;
      size_t g = (rowbase + it * 8 + ri) * 1024 + h * 64;
      if (ci < 64) ks[ri][ci] = kv[g + ci];
      else         vs[ri][ci - 64] = kv[g + 512 + (ci - 64)];
    }
    __syncthreads();
#pragma unroll
    for (int ri = 0; ri < 8; ++ri) {
      float a[4], v4[4];
#pragma unroll
      for (int i = 0; i < 4; ++i) a[i] = ks[ri][tr + i];
#pragma unroll
      for (int j = 0; j < 4; ++j) v4[j] = vs[ri][tc + j];
#pragma unroll
      for (int i = 0; i < 4; ++i)
#pragma unroll
        for (int j = 0; j < 4; ++j)
          acc[i][j] = fmaf(a[i], v4[j], acc[i][j]);
    }
  }
  const float scl = 1.0f / (float)N_TOK;
#pragma unroll
  for (int i = 0; i < 4; ++i)
#pragma unroll
    for (int j = 0; j < 4; ++j)
      atomicAdd(&kvm[(size_t)bh * 4096 + (tr + i) * 64 + (tc + j)], acc[i][j] * scl);
}

// ---------------------------------------------------------------- y = attn + dwconv (overwrites q)
// one block per token row; thread handles channels t and t+256.
__global__ __launch_bounds__(256) void y_kernel(float* __restrict__ q,
                                                const float* __restrict__ kv,
                                                const float* __restrict__ kvm,
                                                const float* __restrict__ z,
                                                const float* __restrict__ wconv,
                                                const float* __restrict__ bconv) {
  __shared__ float qs[512];
  __shared__ float wl[25][64];
  __shared__ float bl[64];
  const int row = blockIdx.x;
  const int b = row >> 14, n = row & (N_TOK - 1);
  const int y0 = n >> 7, x0 = n & 127;
  const int t = threadIdx.x;
  qs[t] = q[(size_t)row * 512 + t];
  qs[t + 256] = q[(size_t)row * 512 + t + 256];
  for (int idx = t; idx < 1600; idx += 256) {
    int dd = idx / 25, kk = idx % 25;
    wl[kk][dd] = wconv[idx];
  }
  if (t < 64) bl[t] = bconv[t];
  __syncthreads();

  float out[2];
#pragma unroll
  for (int ci = 0; ci < 2; ++ci) {
    const int c = t + ci * 256;
    const int h = c >> 6, dd = c & 63;
    const int bh = b * 8 + h;
    // attention part
    const float* km = kvm + (size_t)bh * 4096 + dd;
    float acc = 0.f;
#pragma unroll
    for (int d = 0; d < 64; ++d) acc = fmaf(qs[h * 64 + d], km[d * 64], acc);
    acc *= z[(size_t)bh * N_TOK + n];
    // depthwise 5x5 conv on v
    float cv = bl[dd];
    const float* vbase = kv + ((size_t)b * N_TOK) * 1024 + 512 + h * 64 + dd;
#pragma unroll
    for (int ky = 0; ky < 5; ++ky) {
      int yy = y0 + ky - 2;
      if ((unsigned)yy < 128u) {
#pragma unroll
        for (int kx = 0; kx < 5; ++kx) {
          int xx = x0 + kx - 2;
          if ((unsigned)xx < 128u)
            cv = fmaf(wl[ky * 5 + kx][dd], vbase[(size_t)(yy * 128 + xx) * 1024], cv);
        }
      }
    }
    out[ci] = acc + cv;
  }
  q[(size_t)row * 512 + t] = out[0];
  q[(size_t)row * 512 + t + 256] = out[1];
}

// ---------------------------------------------------------------- launch
extern "C" void kernel_launch(void* const* d_in, const int* in_sizes, int n_in,
                              void* d_out, int out_size, void* d_ws, size_t ws_size,
                              hipStream_t stream) {
  (void)n_in; (void)out_size;
  const float* x     = (const float*)d_in[0];
  const float* Wq    = (const float*)d_in[1];
  const float* bq    = (const float*)d_in[2];
  const float* Wkv   = (const float*)d_in[3];
  const float* bkv   = (const float*)d_in[4];
  const float* Wp    = (const float*)d_in[5];
  const float* bp    = (const float*)d_in[6];
  const float* ff    = (const float*)d_in[7];
  const float* scale = (const float*)d_in[8];
  const float* dwc_w = (const float*)d_in[9];
  const float* dwc_b = (const float*)d_in[10];
  // d_in[11]=H, d_in[12]=W assumed 128 (per setup_inputs)

  const int B = in_sizes[0] / (N_TOK * CDIM);   // 4
  const int M = B * N_TOK;                      // 65536

  float* q    = (float*)d_ws;                          // M x 512
  float* kv   = q + (size_t)M * 512;                   // M x 1024 (k | v)
  float* ksum = kv + (size_t)M * 1024;                 // B x 512
  float* kvm  = ksum + (size_t)B * 512;                // B*8 x 64 x 64
  float* z    = kvm + (size_t)B * 8 * 4096;            // B*8 x N

  size_t need = ((size_t)M * 1536 + (size_t)B * 512 + (size_t)B * 8 * 4096 +
                 (size_t)B * 8 * N_TOK) * sizeof(float);
  if (ws_size < need) {
    fprintf(stderr, "kernel_launch: ws too small (%zu < %zu)\n", ws_size, need);
    return;
  }

  const int nsmall = B * 512 + B * 8 * 4096;   // ksum + kvm contiguous
  zero_kernel<<<(nsmall + 255) / 256, 256, 0, stream>>>(ksum, nsmall);

  gemm_nt<<<dim3(M / 128, 512 / 128), 256, 0, stream>>>(x, Wq, bq, q, CDIM, 512);
  gemm_nt<<<dim3(M / 128, 1024 / 128), 256, 0, stream>>>(x, Wkv, bkv, kv, CDIM, 1024);
  nonlin_kernel<<<M, 256, 0, stream>>>(q, kv, scale, ff);
  kmean_kernel<<<dim3(32, B), 256, 0, stream>>>(kv, ksum);
  z_kernel<<<M / 4, 256, 0, stream>>>(q, ksum, z);
  kvmat_kernel<<<dim3(32, B * 8), 256, 0, stream>>>(kv, kvm);
  y_kernel<<<M, 256, 0, stream>>>(q, kv, kvm, z, dwc_w, dwc_b);
  gemm_nt<<<dim3(M / 128, 512 / 128), 256, 0, stream>>>(q, Wp, bp, (float*)d_out, CDIM, 512);
}

// Round 2
// 2654.456 us; speedup vs baseline: 1.8600x; 1.8600x over previous
//
#include <hip/hip_runtime.h>
#include <cstdio>

#define N_TOK 16384
#define CDIM  512

// ---------------------------------------------------------------- zero
__global__ void zero_kernel(float* __restrict__ p, int n) {
  int i = blockIdx.x * blockDim.x + threadIdx.x;
  if (i < n) p[i] = 0.f;
}

// ---------------------------------------------------------------- GEMM
// C[M x Nout] = A[M x K] * B[Nout x K]^T + bias   (all row-major, lda=ldb=K)
// grid = (M/128, Nout/128), block = 256. BM=BN=128, BK=16, 8x8 per thread.
__global__ __launch_bounds__(256) void gemm_nt(const float* __restrict__ A,
                                               const float* __restrict__ B,
                                               const float* __restrict__ bias,
                                               float* __restrict__ C,
                                               int K, int ldc) {
  __shared__ float As[16][132];
  __shared__ float Bs[16][132];
  const int t = threadIdx.x;
  const size_t bm = (size_t)blockIdx.x * 128;
  const size_t bn = (size_t)blockIdx.y * 128;
  const int arow = t >> 2;          // 0..63
  const int ak4  = (t & 3) * 4;     // 0,4,8,12
  const int tr   = (t >> 4) * 8;    // 0..120
  const int tc   = (t & 15) * 8;    // 0..120
  float acc[8][8] = {};
  const float* Ab = A + (bm + arow) * (size_t)K + ak4;
  const float* Bb = B + (bn + arow) * (size_t)K + ak4;
  for (int k0 = 0; k0 < K; k0 += 16) {
    float4 av0 = *(const float4*)(Ab + k0);
    float4 av1 = *(const float4*)(Ab + (size_t)64 * K + k0);
    float4 bv0 = *(const float4*)(Bb + k0);
    float4 bv1 = *(const float4*)(Bb + (size_t)64 * K + k0);
    __syncthreads();
    As[ak4+0][arow]    = av0.x; As[ak4+1][arow]    = av0.y;
    As[ak4+2][arow]    = av0.z; As[ak4+3][arow]    = av0.w;
    As[ak4+0][arow+64] = av1.x; As[ak4+1][arow+64] = av1.y;
    As[ak4+2][arow+64] = av1.z; As[ak4+3][arow+64] = av1.w;
    Bs[ak4+0][arow]    = bv0.x; Bs[ak4+1][arow]    = bv0.y;
    Bs[ak4+2][arow]    = bv0.z; Bs[ak4+3][arow]    = bv0.w;
    Bs[ak4+0][arow+64] = bv1.x; Bs[ak4+1][arow+64] = bv1.y;
    Bs[ak4+2][arow+64] = bv1.z; Bs[ak4+3][arow+64] = bv1.w;
    __syncthreads();
#pragma unroll
    for (int kk = 0; kk < 16; ++kk) {
      float a[8], b[8];
      *(float4*)&a[0] = *(const float4*)&As[kk][tr];
      *(float4*)&a[4] = *(const float4*)&As[kk][tr + 4];
      *(float4*)&b[0] = *(const float4*)&Bs[kk][tc];
      *(float4*)&b[4] = *(const float4*)&Bs[kk][tc + 4];
#pragma unroll
      for (int i = 0; i < 8; ++i)
#pragma unroll
        for (int j = 0; j < 8; ++j)
          acc[i][j] = fmaf(a[i], b[j], acc[i][j]);
    }
  }
#pragma unroll
  for (int i = 0; i < 8; ++i) {
    float o[8];
#pragma unroll
    for (int j = 0; j < 8; ++j) o[j] = acc[i][j] + bias[bn + tc + j];
    float* Cr = C + (bm + tr + i) * (size_t)ldc + bn + tc;
    *(float4*)&Cr[0] = *(float4*)&o[0];
    *(float4*)&Cr[4] = *(float4*)&o[4];
  }
}

// ---------------------------------------------------------------- nonlinearity
__global__ __launch_bounds__(256) void nonlin_kernel(float* __restrict__ q,
                                                     float* __restrict__ kv,
                                                     const float* __restrict__ scale,
                                                     const float* __restrict__ ff) {
  __shared__ float red[8];
  const int row = blockIdx.x;
  const int t = threadIdx.x;
  const int wid = t >> 6, lane = t & 63;
  float* qr = q + (size_t)row * 512;
  float* kr = kv + (size_t)row * 1024;

  float sc0 = scale[t], sc1 = scale[t + 256];
  float s0 = (sc0 > 20.f) ? sc0 : log1pf(expf(sc0));
  float s1 = (sc1 > 20.f) ? sc1 : log1pf(expf(sc1));
  float f0 = ff[t], f1 = ff[t + 256];

  float q0 = (fmaxf(qr[t], 0.f) + 1e-6f) / s0;
  float q1 = (fmaxf(qr[t + 256], 0.f) + 1e-6f) / s1;
  float k0 = (fmaxf(kr[t], 0.f) + 1e-6f) / s0;
  float k1 = (fmaxf(kr[t + 256], 0.f) + 1e-6f) / s1;

  float sq = q0 * q0 + q1 * q1;
  float sk = k0 * k0 + k1 * k1;
  for (int off = 32; off > 0; off >>= 1) {
    sq += __shfl_down(sq, off);
    sk += __shfl_down(sk, off);
  }
  if (lane == 0) { red[wid * 2] = sq; red[wid * 2 + 1] = sk; }
  __syncthreads();
  float qn = sqrtf(red[0] + red[2] + red[4] + red[6]);
  float kn = sqrtf(red[1] + red[3] + red[5] + red[7]);
  __syncthreads();

  float pq0 = powf(q0, f0), pq1 = powf(q1, f1);
  float pk0 = powf(k0, f0), pk1 = powf(k1, f1);

  float sq2 = pq0 * pq0 + pq1 * pq1;
  float sk2 = pk0 * pk0 + pk1 * pk1;
  for (int off = 32; off > 0; off >>= 1) {
    sq2 += __shfl_down(sq2, off);
    sk2 += __shfl_down(sk2, off);
  }
  if (lane == 0) { red[wid * 2] = sq2; red[wid * 2 + 1] = sk2; }
  __syncthreads();
  float pqn = sqrtf(red[0] + red[2] + red[4] + red[6]);
  float pkn = sqrtf(red[1] + red[3] + red[5] + red[7]);

  float qs = qn / pqn, ks = kn / pkn;
  qr[t] = pq0 * qs;
  qr[t + 256] = pq1 * qs;
  kr[t] = pk0 * ks;
  kr[t + 256] = pk1 * ks;
}

// ---------------------------------------------------------------- k sum over N
// grid = (128, B); each block sums 128 rows for all 512 channels, atomicAdd.
__global__ __launch_bounds__(256) void kmean_kernel(const float* __restrict__ kv,
                                                    float* __restrict__ ksum) {
  const int b = blockIdx.y, ch = blockIdx.x, t = threadIdx.x;
  size_t base = ((size_t)b * N_TOK + (size_t)ch * 128) * 1024;
  float a0 = 0.f, a1 = 0.f;
  for (int i = 0; i < 128; ++i) {
    const float* r = kv + base + (size_t)i * 1024;
    a0 += r[t];
    a1 += r[t + 256];
  }
  atomicAdd(&ksum[b * 512 + t], a0);
  atomicAdd(&ksum[b * 512 + t + 256], a1);
}

// ---------------------------------------------------------------- z = 1/(q . k_mean + eps)
__global__ __launch_bounds__(256) void z_kernel(const float* __restrict__ q,
                                                const float* __restrict__ ksum,
                                                float* __restrict__ z) {
  const int t = threadIdx.x;
  const int w = t >> 6, lane = t & 63;
  const int row = blockIdx.x * 4 + w;
  const int b = row >> 14, n = row & (N_TOK - 1);
  const int hh = lane >> 3, j = lane & 7;
  const float* qr = q + (size_t)row * 512 + hh * 64 + j * 8;
  const float* kr = ksum + b * 512 + hh * 64 + j * 8;
  float p = 0.f;
#pragma unroll
  for (int i = 0; i < 8; ++i) p += qr[i] * kr[i];
  p += __shfl_xor(p, 1);
  p += __shfl_xor(p, 2);
  p += __shfl_xor(p, 4);
  if (j == 0) {
    float dot = p * (1.0f / (float)N_TOK);  // ksum -> mean
    z[((size_t)(b * 8 + hh)) * N_TOK + n] = 1.0f / (dot + 1e-6f);
  }
}

// ---------------------------------------------------------------- kv_mat[bh] = k^T v / N
__global__ __launch_bounds__(256) void kvmat_kernel(const float* __restrict__ kv,
                                                    float* __restrict__ kvm) {
  __shared__ float ks[8][64];
  __shared__ float vs[8][64];
  const int bh = blockIdx.y;
  const int b = bh >> 3, h = bh & 7;
  const int chunk = blockIdx.x;
  const int t = threadIdx.x;
  const int tr = (t >> 4) * 4, tc = (t & 15) * 4;
  float acc[4][4] = {};
  size_t rowbase = (size_t)b * N_TOK + (size_t)chunk * 512;
  for (int it = 0; it < 64; ++it) {
    __syncthreads();
#pragma unroll
    for (int l = 0; l < 4; ++l) {
      int idx = l * 256 + t;
      int ri = idx >> 7, ci = idx & 127;
      size_t g = (rowbase + it * 8 + ri) * 1024 + h * 64;
      if (ci < 64) ks[ri][ci] = kv[g + ci];
      else         vs[ri][ci - 64] = kv[g + 512 + (ci - 64)];
    }
    __syncthreads();
#pragma unroll
    for (int ri = 0; ri < 8; ++ri) {
      float a[4], v4[4];
#pragma unroll
      for (int i = 0; i < 4; ++i) a[i] = ks[ri][tr + i];
#pragma unroll
      for (int j = 0; j < 4; ++j) v4[j] = vs[ri][tc + j];
#pragma unroll
      for (int i = 0; i < 4; ++i)
#pragma unroll
        for (int j = 0; j < 4; ++j)
          acc[i][j] = fmaf(a[i], v4[j], acc[i][j]);
    }
  }
  const float scl = 1.0f / (float)N_TOK;
#pragma unroll
  for (int i = 0; i < 4; ++i)
#pragma unroll
    for (int j = 0; j < 4; ++j)
      atomicAdd(&kvm[(size_t)bh * 4096 + (tr + i) * 64 + (tc + j)], acc[i][j] * scl);
}

// ---------------------------------------------------------------- attn: q <- (q @ kvm) * z   (in-place per head)
// grid = (N_TOK/64, B*8), block 256. Stages kvm (64x64) and a 64-token q tile in LDS.
__global__ __launch_bounds__(256) void attn_kernel(float* __restrict__ q,
                                                   const float* __restrict__ kvm,
                                                   const float* __restrict__ z) {
  __shared__ float km[64][64];   // [d_in][d_out] : lanes read consecutive d_out -> conflict-free
  __shared__ float qs[64][64];   // [tok][d_in]   : wave-uniform broadcast reads
  const int bh = blockIdx.y;
  const int b = bh >> 3, h = bh & 7;
  const int tok0 = blockIdx.x * 64;
  const int t = threadIdx.x;
  const size_t kvm_base = (size_t)bh * 4096;
  const size_t qbase = ((size_t)b * N_TOK + tok0) * 512 + h * 64;
#pragma unroll
  for (int i = 0; i < 16; ++i) {
    int idx = i * 256 + t;
    km[idx >> 6][idx & 63] = kvm[kvm_base + idx];
    qs[idx >> 6][idx & 63] = q[qbase + (size_t)(idx >> 6) * 512 + (idx & 63)];
  }
  __syncthreads();
  const int d = t & 63, slot = t >> 6;   // slot uniform within wave
  const float* zrow = z + (size_t)bh * N_TOK + tok0;
  for (int i = 0; i < 16; ++i) {
    const int tok = i * 4 + slot;
    float a0 = 0.f, a1 = 0.f, a2 = 0.f, a3 = 0.f;
#pragma unroll
    for (int din = 0; din < 64; din += 4) {
      a0 = fmaf(qs[tok][din + 0], km[din + 0][d], a0);
      a1 = fmaf(qs[tok][din + 1], km[din + 1][d], a1);
      a2 = fmaf(qs[tok][din + 2], km[din + 2][d], a2);
      a3 = fmaf(qs[tok][din + 3], km[din + 3][d], a3);
    }
    q[qbase + (size_t)tok * 512 + d] = ((a0 + a1) + (a2 + a3)) * zrow[tok];
  }
}

// ---------------------------------------------------------------- depthwise 5x5 conv on v, accumulated into y (+=)
// grid = (8, 8, B*8*2): 16x16 pixel tile, 32 channels per block. Halo tile in LDS.
__global__ __launch_bounds__(256) void conv_kernel(const float* __restrict__ kv,
                                                   float* __restrict__ y,
                                                   const float* __restrict__ wconv,
                                                   const float* __restrict__ bconv) {
  __shared__ float vt[20 * 20 * 32];   // [ly][lx][c]  51.2 KB
  const int zidx = blockIdx.z;
  const int bh = zidx >> 1, chalf = zidx & 1;
  const int b = bh >> 3, h = bh & 7;
  const int c0 = chalf * 32;
  const int tx0 = blockIdx.x * 16, ty0 = blockIdx.y * 16;
  const int t = threadIdx.x;
  const int c = t & 31;
  const size_t vbase = (size_t)b * N_TOK * 1024 + 512 + h * 64 + c0 + c;
  // stage halo tile (zero-padded)
  for (int i = 0; i < 50; ++i) {
    int idx = i * 256 + t;
    int pix = idx >> 5;               // 0..399
    int lx = pix % 20, ly = pix / 20;
    int gx = tx0 + lx - 2, gy = ty0 + ly - 2;
    float val = 0.f;
    if ((unsigned)gx < 128u && (unsigned)gy < 128u)
      val = kv[vbase + ((size_t)(gy * 128 + gx)) * 1024 - (size_t)c + (size_t)(idx & 31)];
    vt[pix * 32 + (idx & 31)] = val;
  }
  // weights + bias in registers
  const int dd = c0 + c;
  float w[25];
#pragma unroll
  for (int k = 0; k < 25; ++k) w[k] = wconv[dd * 25 + k];
  const float bb = bconv[dd];
  __syncthreads();
  const int slot = t >> 5;   // 8 pixel slots
  for (int i = 0; i < 32; ++i) {
    const int pix = i * 8 + slot;
    const int px = pix & 15, py = pix >> 4;
    float acc = bb;
#pragma unroll
    for (int ky = 0; ky < 5; ++ky)
#pragma unroll
      for (int kx = 0; kx < 5; ++kx)
        acc = fmaf(w[ky * 5 + kx], vt[((py + ky) * 20 + (px + kx)) * 32 + c], acc);
    size_t o = ((size_t)b * N_TOK + (size_t)(ty0 + py) * 128 + (tx0 + px)) * 512 + h * 64 + dd;
    y[o] += acc;
  }
}

// ---------------------------------------------------------------- launch
extern "C" void kernel_launch(void* const* d_in, const int* in_sizes, int n_in,
                              void* d_out, int out_size, void* d_ws, size_t ws_size,
                              hipStream_t stream) {
  (void)n_in; (void)out_size;
  const float* x     = (const float*)d_in[0];
  const float* Wq    = (const float*)d_in[1];
  const float* bq    = (const float*)d_in[2];
  const float* Wkv   = (const float*)d_in[3];
  const float* bkv   = (const float*)d_in[4];
  const float* Wp    = (const float*)d_in[5];
  const float* bp    = (const float*)d_in[6];
  const float* ff    = (const float*)d_in[7];
  const float* scale = (const float*)d_in[8];
  const float* dwc_w = (const float*)d_in[9];
  const float* dwc_b = (const float*)d_in[10];

  const int B = in_sizes[0] / (N_TOK * CDIM);   // 4
  const int M = B * N_TOK;                      // 65536

  float* q    = (float*)d_ws;                          // M x 512
  float* kv   = q + (size_t)M * 512;                   // M x 1024 (k | v)
  float* ksum = kv + (size_t)M * 1024;                 // B x 512
  float* kvm  = ksum + (size_t)B * 512;                // B*8 x 64 x 64
  float* z    = kvm + (size_t)B * 8 * 4096;            // B*8 x N

  size_t need = ((size_t)M * 1536 + (size_t)B * 512 + (size_t)B * 8 * 4096 +
                 (size_t)B * 8 * N_TOK) * sizeof(float);
  if (ws_size < need) {
    fprintf(stderr, "kernel_launch: ws too small (%zu < %zu)\n", ws_size, need);
    return;
  }

  const int nsmall = B * 512 + B * 8 * 4096;   // ksum + kvm contiguous
  zero_kernel<<<(nsmall + 255) / 256, 256, 0, stream>>>(ksum, nsmall);

  gemm_nt<<<dim3(M / 128, 512 / 128), 256, 0, stream>>>(x, Wq, bq, q, CDIM, 512);
  gemm_nt<<<dim3(M / 128, 1024 / 128), 256, 0, stream>>>(x, Wkv, bkv, kv, CDIM, 1024);
  nonlin_kernel<<<M, 256, 0, stream>>>(q, kv, scale, ff);
  kmean_kernel<<<dim3(128, B), 256, 0, stream>>>(kv, ksum);
  z_kernel<<<M / 4, 256, 0, stream>>>(q, ksum, z);
  kvmat_kernel<<<dim3(32, B * 8), 256, 0, stream>>>(kv, kvm);
  attn_kernel<<<dim3(N_TOK / 64, B * 8), 256, 0, stream>>>(q, kvm, z);
  conv_kernel<<<dim3(8, 8, B * 8 * 2), 256, 0, stream>>>(kv, q, dwc_w, dwc_b);
  gemm_nt<<<dim3(M / 128, 512 / 128), 256, 0, stream>>>(q, Wp, bp, (float*)d_out, CDIM, 512);
}

// Round 3
// 2651.623 us; speedup vs baseline: 1.8620x; 1.0011x over previous
//
#include <hip/hip_runtime.h>
#include <cstdio>

#define N_TOK 16384
#define CDIM  512

typedef unsigned short ushort_t;
typedef __attribute__((ext_vector_type(8))) __bf16 bf16x8;
typedef __attribute__((ext_vector_type(4))) float f32x4;

// ---------------------------------------------------------------- helpers
__device__ __forceinline__ ushort_t f2bf(float f) {
  union { float f; unsigned u; } v; v.f = f;
  unsigned r = v.u + 0x7FFFu + ((v.u >> 16) & 1u);   // RN-even
  return (ushort_t)(r >> 16);
}
__device__ __forceinline__ float bf2f(ushort_t h) {
  union { unsigned u; float f; } v; v.u = ((unsigned)h) << 16;
  return v.f;
}
__device__ __forceinline__ void gl_lds16(const ushort_t* g, ushort_t* l) {
  __builtin_amdgcn_global_load_lds((const __attribute__((address_space(1))) void*)g,
                                   (__attribute__((address_space(3))) void*)l, 16, 0, 0);
}

// ---------------------------------------------------------------- zero
__global__ void zero_kernel(float* __restrict__ p, int n) {
  int i = blockIdx.x * blockDim.x + threadIdx.x;
  if (i < n) p[i] = 0.f;
}

// ---------------------------------------------------------------- fp32 -> bf16 hi/lo planes
__global__ __launch_bounds__(256) void split_kernel(const float* __restrict__ in,
                                                    ushort_t* __restrict__ hi,
                                                    ushort_t* __restrict__ lo, int n4) {
  int i = blockIdx.x * blockDim.x + threadIdx.x;
  const int stride = gridDim.x * blockDim.x;
  for (; i < n4; i += stride) {
    float4 v = ((const float4*)in)[i];
    ushort4 h, l;
    h.x = f2bf(v.x); l.x = f2bf(v.x - bf2f(h.x));
    h.y = f2bf(v.y); l.y = f2bf(v.y - bf2f(h.y));
    h.z = f2bf(v.z); l.z = f2bf(v.z - bf2f(h.z));
    h.w = f2bf(v.w); l.w = f2bf(v.w - bf2f(h.w));
    ((ushort4*)hi)[i] = h;
    ((ushort4*)lo)[i] = l;
  }
}

// ---------------------------------------------------------------- split-bf16 MFMA GEMM
// C[M x Nout] = A[M x K] * B[Nout x K]^T + bias, via hi/lo bf16 planes:
// C = Ah*Bh + Ah*Bl + Al*Bh (fp32 accum). grid=(M/128, Nout/128), 256 thr (4 waves).
// Each wave owns a 64x64 quadrant: 4x4 fragments of 16x16x32 MFMA.
__global__ __launch_bounds__(256) void gemm_s3(const ushort_t* __restrict__ Ah,
                                               const ushort_t* __restrict__ Al,
                                               const ushort_t* __restrict__ Bh,
                                               const ushort_t* __restrict__ Bl,
                                               const float* __restrict__ bias,
                                               float* __restrict__ C,
                                               const int K, const int ldc) {
  __shared__ __align__(16) ushort_t Ash[128 * 32];
  __shared__ __align__(16) ushort_t Asl[128 * 32];
  __shared__ __align__(16) ushort_t Bsh[128 * 32];
  __shared__ __align__(16) ushort_t Bsl[128 * 32];
  const int t = threadIdx.x;
  const int w = t >> 6, lane = t & 63;
  const int wr = w >> 1, wc = w & 1;
  const size_t bm = (size_t)blockIdx.x * 128;
  const size_t bn = (size_t)blockIdx.y * 128;
  // staging geometry: wave w stages rows [w*32, w*32+32) of each 128x32 tile,
  // two global_load_lds calls of 16 rows each (4 lanes/row, 8 bf16/lane).
  const int r0a = w * 32;            // first 16-row group
  const int r0b = w * 32 + 16;       // second
  const int lrow = lane >> 2;        // 0..15 row within group
  const int scol = (lane & 3) * 8;   // k-element offset

  f32x4 acc[4][4] = {};

  const int nsteps = K >> 5;
  for (int s = 0; s < nsteps; ++s) {
    const int k0 = s << 5;
    __syncthreads();   // all waves done reading LDS from previous step
    {
      const size_t ga0 = (bm + r0a + lrow) * (size_t)K + k0 + scol;
      const size_t ga1 = (bm + r0b + lrow) * (size_t)K + k0 + scol;
      const size_t gb0 = (bn + r0a + lrow) * (size_t)K + k0 + scol;
      const size_t gb1 = (bn + r0b + lrow) * (size_t)K + k0 + scol;
      gl_lds16(Ah + ga0, Ash + r0a * 32);
      gl_lds16(Ah + ga1, Ash + r0b * 32);
      gl_lds16(Al + ga0, Asl + r0a * 32);
      gl_lds16(Al + ga1, Asl + r0b * 32);
      gl_lds16(Bh + gb0, Bsh + r0a * 32);
      gl_lds16(Bh + gb1, Bsh + r0b * 32);
      gl_lds16(Bl + gb0, Bsl + r0a * 32);
      gl_lds16(Bl + gb1, Bsl + r0b * 32);
    }
    __syncthreads();   // includes vmcnt(0) drain of global_load_lds

    const int lr = lane & 15, lk = (lane >> 4) * 8;
    bf16x8 ah[4], al[4], bh[4], bl[4];
#pragma unroll
    for (int i = 0; i < 4; ++i) {
      ah[i] = *(const bf16x8*)&Ash[(wr * 64 + i * 16 + lr) * 32 + lk];
      al[i] = *(const bf16x8*)&Asl[(wr * 64 + i * 16 + lr) * 32 + lk];
      bh[i] = *(const bf16x8*)&Bsh[(wc * 64 + i * 16 + lr) * 32 + lk];
      bl[i] = *(const bf16x8*)&Bsl[(wc * 64 + i * 16 + lr) * 32 + lk];
    }
#pragma unroll
    for (int mi = 0; mi < 4; ++mi)
#pragma unroll
      for (int ni = 0; ni < 4; ++ni) {
        acc[mi][ni] = __builtin_amdgcn_mfma_f32_16x16x32_bf16(ah[mi], bh[ni], acc[mi][ni], 0, 0, 0);
        acc[mi][ni] = __builtin_amdgcn_mfma_f32_16x16x32_bf16(ah[mi], bl[ni], acc[mi][ni], 0, 0, 0);
        acc[mi][ni] = __builtin_amdgcn_mfma_f32_16x16x32_bf16(al[mi], bh[ni], acc[mi][ni], 0, 0, 0);
      }
  }

  // epilogue: C/D layout col=lane&15, row=(lane>>4)*4+reg
  const int lr = lane & 15;
  const int rg = (lane >> 4) << 2;
#pragma unroll
  for (int ni = 0; ni < 4; ++ni) {
    const int col = (int)bn + wc * 64 + ni * 16 + lr;
    const float bs = bias[col];
#pragma unroll
    for (int mi = 0; mi < 4; ++mi) {
      float* Cp = C + (bm + wr * 64 + mi * 16 + rg) * (size_t)ldc + col;
#pragma unroll
      for (int j = 0; j < 4; ++j)
        Cp[(size_t)j * ldc] = acc[mi][ni][j] + bs;
    }
  }
}

// ---------------------------------------------------------------- fp32 fallback GEMM (ws too small)
__global__ __launch_bounds__(256) void gemm_nt(const float* __restrict__ A,
                                               const float* __restrict__ B,
                                               const float* __restrict__ bias,
                                               float* __restrict__ C,
                                               int K, int ldc) {
  __shared__ float As[16][132];
  __shared__ float Bs[16][132];
  const int t = threadIdx.x;
  const size_t bm = (size_t)blockIdx.x * 128;
  const size_t bn = (size_t)blockIdx.y * 128;
  const int arow = t >> 2;
  const int ak4  = (t & 3) * 4;
  const int tr   = (t >> 4) * 8;
  const int tc   = (t & 15) * 8;
  float acc[8][8] = {};
  const float* Ab = A + (bm + arow) * (size_t)K + ak4;
  const float* Bb = B + (bn + arow) * (size_t)K + ak4;
  for (int k0 = 0; k0 < K; k0 += 16) {
    float4 av0 = *(const float4*)(Ab + k0);
    float4 av1 = *(const float4*)(Ab + (size_t)64 * K + k0);
    float4 bv0 = *(const float4*)(Bb + k0);
    float4 bv1 = *(const float4*)(Bb + (size_t)64 * K + k0);
    __syncthreads();
    As[ak4+0][arow]    = av0.x; As[ak4+1][arow]    = av0.y;
    As[ak4+2][arow]    = av0.z; As[ak4+3][arow]    = av0.w;
    As[ak4+0][arow+64] = av1.x; As[ak4+1][arow+64] = av1.y;
    As[ak4+2][arow+64] = av1.z; As[ak4+3][arow+64] = av1.w;
    Bs[ak4+0][arow]    = bv0.x; Bs[ak4+1][arow]    = bv0.y;
    Bs[ak4+2][arow]    = bv0.z; Bs[ak4+3][arow]    = bv0.w;
    Bs[ak4+0][arow+64] = bv1.x; Bs[ak4+1][arow+64] = bv1.y;
    Bs[ak4+2][arow+64] = bv1.z; Bs[ak4+3][arow+64] = bv1.w;
    __syncthreads();
#pragma unroll
    for (int kk = 0; kk < 16; ++kk) {
      float a[8], b[8];
      *(float4*)&a[0] = *(const float4*)&As[kk][tr];
      *(float4*)&a[4] = *(const float4*)&As[kk][tr + 4];
      *(float4*)&b[0] = *(const float4*)&Bs[kk][tc];
      *(float4*)&b[4] = *(const float4*)&Bs[kk][tc + 4];
#pragma unroll
      for (int i = 0; i < 8; ++i)
#pragma unroll
        for (int j = 0; j < 8; ++j)
          acc[i][j] = fmaf(a[i], b[j], acc[i][j]);
    }
  }
#pragma unroll
  for (int i = 0; i < 8; ++i) {
    float o[8];
#pragma unroll
    for (int j = 0; j < 8; ++j) o[j] = acc[i][j] + bias[bn + tc + j];
    float* Cr = C + (bm + tr + i) * (size_t)ldc + bn + tc;
    *(float4*)&Cr[0] = *(float4*)&o[0];
    *(float4*)&Cr[4] = *(float4*)&o[4];
  }
}

// ---------------------------------------------------------------- nonlinearity
__global__ __launch_bounds__(256) void nonlin_kernel(float* __restrict__ q,
                                                     float* __restrict__ kv,
                                                     const float* __restrict__ scale,
                                                     const float* __restrict__ ff) {
  __shared__ float red[8];
  const int row = blockIdx.x;
  const int t = threadIdx.x;
  const int wid = t >> 6, lane = t & 63;
  float* qr = q + (size_t)row * 512;
  float* kr = kv + (size_t)row * 1024;

  float sc0 = scale[t], sc1 = scale[t + 256];
  float s0 = (sc0 > 20.f) ? sc0 : log1pf(expf(sc0));
  float s1 = (sc1 > 20.f) ? sc1 : log1pf(expf(sc1));
  float f0 = ff[t], f1 = ff[t + 256];

  float q0 = (fmaxf(qr[t], 0.f) + 1e-6f) / s0;
  float q1 = (fmaxf(qr[t + 256], 0.f) + 1e-6f) / s1;
  float k0 = (fmaxf(kr[t], 0.f) + 1e-6f) / s0;
  float k1 = (fmaxf(kr[t + 256], 0.f) + 1e-6f) / s1;

  float sq = q0 * q0 + q1 * q1;
  float sk = k0 * k0 + k1 * k1;
  for (int off = 32; off > 0; off >>= 1) {
    sq += __shfl_down(sq, off);
    sk += __shfl_down(sk, off);
  }
  if (lane == 0) { red[wid * 2] = sq; red[wid * 2 + 1] = sk; }
  __syncthreads();
  float qn = sqrtf(red[0] + red[2] + red[4] + red[6]);
  float kn = sqrtf(red[1] + red[3] + red[5] + red[7]);
  __syncthreads();

  float pq0 = powf(q0, f0), pq1 = powf(q1, f1);
  float pk0 = powf(k0, f0), pk1 = powf(k1, f1);

  float sq2 = pq0 * pq0 + pq1 * pq1;
  float sk2 = pk0 * pk0 + pk1 * pk1;
  for (int off = 32; off > 0; off >>= 1) {
    sq2 += __shfl_down(sq2, off);
    sk2 += __shfl_down(sk2, off);
  }
  if (lane == 0) { red[wid * 2] = sq2; red[wid * 2 + 1] = sk2; }
  __syncthreads();
  float pqn = sqrtf(red[0] + red[2] + red[4] + red[6]);
  float pkn = sqrtf(red[1] + red[3] + red[5] + red[7]);

  float qs = qn / pqn, ks = kn / pkn;
  qr[t] = pq0 * qs;
  qr[t + 256] = pq1 * qs;
  kr[t] = pk0 * ks;
  kr[t + 256] = pk1 * ks;
}

// ---------------------------------------------------------------- k sum over N
__global__ __launch_bounds__(256) void kmean_kernel(const float* __restrict__ kv,
                                                    float* __restrict__ ksum) {
  const int b = blockIdx.y, ch = blockIdx.x, t = threadIdx.x;
  size_t base = ((size_t)b * N_TOK + (size_t)ch * 128) * 1024;
  float a0 = 0.f, a1 = 0.f;
  for (int i = 0; i < 128; ++i) {
    const float* r = kv + base + (size_t)i * 1024;
    a0 += r[t];
    a1 += r[t + 256];
  }
  atomicAdd(&ksum[b * 512 + t], a0);
  atomicAdd(&ksum[b * 512 + t + 256], a1);
}

// ---------------------------------------------------------------- z = 1/(q . k_mean + eps)
__global__ __launch_bounds__(256) void z_kernel(const float* __restrict__ q,
                                                const float* __restrict__ ksum,
                                                float* __restrict__ z) {
  const int t = threadIdx.x;
  const int w = t >> 6, lane = t & 63;
  const int row = blockIdx.x * 4 + w;
  const int b = row >> 14, n = row & (N_TOK - 1);
  const int hh = lane >> 3, j = lane & 7;
  const float* qr = q + (size_t)row * 512 + hh * 64 + j * 8;
  const float* kr = ksum + b * 512 + hh * 64 + j * 8;
  float p = 0.f;
#pragma unroll
  for (int i = 0; i < 8; ++i) p += qr[i] * kr[i];
  p += __shfl_xor(p, 1);
  p += __shfl_xor(p, 2);
  p += __shfl_xor(p, 4);
  if (j == 0) {
    float dot = p * (1.0f / (float)N_TOK);
    z[((size_t)(b * 8 + hh)) * N_TOK + n] = 1.0f / (dot + 1e-6f);
  }
}

// ---------------------------------------------------------------- kv_mat[bh] = k^T v / N
__global__ __launch_bounds__(256) void kvmat_kernel(const float* __restrict__ kv,
                                                    float* __restrict__ kvm) {
  __shared__ float ks[8][64];
  __shared__ float vs[8][64];
  const int bh = blockIdx.y;
  const int b = bh >> 3, h = bh & 7;
  const int chunk = blockIdx.x;
  const int t = threadIdx.x;
  const int tr = (t >> 4) * 4, tc = (t & 15) * 4;
  float acc[4][4] = {};
  size_t rowbase = (size_t)b * N_TOK + (size_t)chunk * 512;
  for (int it = 0; it < 64; ++it) {
    __syncthreads();
#pragma unroll
    for (int l = 0; l < 4; ++l) {
      int idx = l * 256 + t;
      int ri = idx >> 7, ci = idx & 127;
      size_t g = (rowbase + it * 8 + ri) * 1024 + h * 64;
      if (ci < 64) ks[ri][ci] = kv[g + ci];
      else         vs[ri][ci - 64] = kv[g + 512 + (ci - 64)];
    }
    __syncthreads();
#pragma unroll
    for (int ri = 0; ri < 8; ++ri) {
      float a[4], v4[4];
#pragma unroll
      for (int i = 0; i < 4; ++i) a[i] = ks[ri][tr + i];
#pragma unroll
      for (int j = 0; j < 4; ++j) v4[j] = vs[ri][tc + j];
#pragma unroll
      for (int i = 0; i < 4; ++i)
#pragma unroll
        for (int j = 0; j < 4; ++j)
          acc[i][j] = fmaf(a[i], v4[j], acc[i][j]);
    }
  }
  const float scl = 1.0f / (float)N_TOK;
#pragma unroll
  for (int i = 0; i < 4; ++i)
#pragma unroll
    for (int j = 0; j < 4; ++j)
      atomicAdd(&kvm[(size_t)bh * 4096 + (tr + i) * 64 + (tc + j)], acc[i][j] * scl);
}

// ---------------------------------------------------------------- attn: q <- (q @ kvm) * z
__global__ __launch_bounds__(256) void attn_kernel(float* __restrict__ q,
                                                   const float* __restrict__ kvm,
                                                   const float* __restrict__ z) {
  __shared__ float km[64][64];
  __shared__ float qs[64][64];
  const int bh = blockIdx.y;
  const int b = bh >> 3, h = bh & 7;
  const int tok0 = blockIdx.x * 64;
  const int t = threadIdx.x;
  const size_t kvm_base = (size_t)bh * 4096;
  const size_t qbase = ((size_t)b * N_TOK + tok0) * 512 + h * 64;
#pragma unroll
  for (int i = 0; i < 16; ++i) {
    int idx = i * 256 + t;
    km[idx >> 6][idx & 63] = kvm[kvm_base + idx];
    qs[idx >> 6][idx & 63] = q[qbase + (size_t)(idx >> 6) * 512 + (idx & 63)];
  }
  __syncthreads();
  const int d = t & 63, slot = t >> 6;
  const float* zrow = z + (size_t)bh * N_TOK + tok0;
  for (int i = 0; i < 16; ++i) {
    const int tok = i * 4 + slot;
    float a0 = 0.f, a1 = 0.f, a2 = 0.f, a3 = 0.f;
#pragma unroll
    for (int din = 0; din < 64; din += 4) {
      a0 = fmaf(qs[tok][din + 0], km[din + 0][d], a0);
      a1 = fmaf(qs[tok][din + 1], km[din + 1][d], a1);
      a2 = fmaf(qs[tok][din + 2], km[din + 2][d], a2);
      a3 = fmaf(qs[tok][din + 3], km[din + 3][d], a3);
    }
    q[qbase + (size_t)tok * 512 + d] = ((a0 + a1) + (a2 + a3)) * zrow[tok];
  }
}

// ---------------------------------------------------------------- depthwise 5x5 conv on v, += into y
__global__ __launch_bounds__(256) void conv_kernel(const float* __restrict__ kv,
                                                   float* __restrict__ y,
                                                   const float* __restrict__ wconv,
                                                   const float* __restrict__ bconv) {
  __shared__ float vt[20 * 20 * 32];
  const int zidx = blockIdx.z;
  const int bh = zidx >> 1, chalf = zidx & 1;
  const int b = bh >> 3, h = bh & 7;
  const int c0 = chalf * 32;
  const int tx0 = blockIdx.x * 16, ty0 = blockIdx.y * 16;
  const int t = threadIdx.x;
  const int c = t & 31;
  const size_t vbase = (size_t)b * N_TOK * 1024 + 512 + h * 64 + c0 + c;
  for (int i = 0; i < 50; ++i) {
    int idx = i * 256 + t;
    int pix = idx >> 5;
    int lx = pix % 20, ly = pix / 20;
    int gx = tx0 + lx - 2, gy = ty0 + ly - 2;
    float val = 0.f;
    if ((unsigned)gx < 128u && (unsigned)gy < 128u)
      val = kv[vbase + ((size_t)(gy * 128 + gx)) * 1024 - (size_t)c + (size_t)(idx & 31)];
    vt[pix * 32 + (idx & 31)] = val;
  }
  const int dd = c0 + c;
  float w[25];
#pragma unroll
  for (int k = 0; k < 25; ++k) w[k] = wconv[dd * 25 + k];
  const float bb = bconv[dd];
  __syncthreads();
  const int slot = t >> 5;
  for (int i = 0; i < 32; ++i) {
    const int pix = i * 8 + slot;
    const int px = pix & 15, py = pix >> 4;
    float acc = bb;
#pragma unroll
    for (int ky = 0; ky < 5; ++ky)
#pragma unroll
      for (int kx = 0; kx < 5; ++kx)
        acc = fmaf(w[ky * 5 + kx], vt[((py + ky) * 20 + (px + kx)) * 32 + c], acc);
    size_t o = ((size_t)b * N_TOK + (size_t)(ty0 + py) * 128 + (tx0 + px)) * 512 + h * 64 + dd;
    y[o] += acc;
  }
}

// ---------------------------------------------------------------- launch
extern "C" void kernel_launch(void* const* d_in, const int* in_sizes, int n_in,
                              void* d_out, int out_size, void* d_ws, size_t ws_size,
                              hipStream_t stream) {
  (void)n_in; (void)out_size;
  const float* x     = (const float*)d_in[0];
  const float* Wq    = (const float*)d_in[1];
  const float* bq    = (const float*)d_in[2];
  const float* Wkv   = (const float*)d_in[3];
  const float* bkv   = (const float*)d_in[4];
  const float* Wp    = (const float*)d_in[5];
  const float* bp    = (const float*)d_in[6];
  const float* ff    = (const float*)d_in[7];
  const float* scale = (const float*)d_in[8];
  const float* dwc_w = (const float*)d_in[9];
  const float* dwc_b = (const float*)d_in[10];

  const int B = in_sizes[0] / (N_TOK * CDIM);   // 4
  const int M = B * N_TOK;                      // 65536

  float* q    = (float*)d_ws;                          // M x 512
  float* kv   = q + (size_t)M * 512;                   // M x 1024 (k | v)
  float* ksum = kv + (size_t)M * 1024;                 // B x 512
  float* kvm  = ksum + (size_t)B * 512;                // 32 x 64 x 64
  float* z    = kvm + (size_t)B * 8 * 4096;            // 32 x N

  size_t f32_count = (size_t)M * 1536 + (size_t)B * 512 + (size_t)B * 8 * 4096 +
                     (size_t)B * 8 * N_TOK;
  // bf16 hi/lo planes after the fp32 region
  ushort_t* xh   = (ushort_t*)(((float*)d_ws) + f32_count);
  ushort_t* xl   = xh + (size_t)M * 512;
  ushort_t* wqh  = xl + (size_t)M * 512;
  ushort_t* wql  = wqh + 512 * 512;
  ushort_t* wkvh = wql + 512 * 512;
  ushort_t* wkvl = wkvh + 1024 * 512;
  ushort_t* wph  = wkvl + 1024 * 512;
  ushort_t* wpl  = wph + 512 * 512;
  size_t need_full = f32_count * 4 +
                     ((size_t)M * 1024 + 2 * (512 * 512 + 1024 * 512 + 512 * 512)) * 2;
  size_t need_min = f32_count * 4;
  const bool use_mfma = (ws_size >= need_full);
  if (ws_size < need_min) {
    fprintf(stderr, "kernel_launch: ws too small (%zu < %zu)\n", ws_size, need_min);
    return;
  }

  const int nsmall = B * 512 + B * 8 * 4096;
  zero_kernel<<<(nsmall + 255) / 256, 256, 0, stream>>>(ksum, nsmall);

  if (use_mfma) {
    split_kernel<<<2048, 256, 0, stream>>>(x, xh, xl, M * 512 / 4);
    split_kernel<<<64, 256, 0, stream>>>(Wq, wqh, wql, 512 * 512 / 4);
    split_kernel<<<128, 256, 0, stream>>>(Wkv, wkvh, wkvl, 1024 * 512 / 4);
    split_kernel<<<64, 256, 0, stream>>>(Wp, wph, wpl, 512 * 512 / 4);
    gemm_s3<<<dim3(M / 128, 4), 256, 0, stream>>>(xh, xl, wqh, wql, bq, q, CDIM, 512);
    gemm_s3<<<dim3(M / 128, 8), 256, 0, stream>>>(xh, xl, wkvh, wkvl, bkv, kv, CDIM, 1024);
  } else {
    gemm_nt<<<dim3(M / 128, 4), 256, 0, stream>>>(x, Wq, bq, q, CDIM, 512);
    gemm_nt<<<dim3(M / 128, 8), 256, 0, stream>>>(x, Wkv, bkv, kv, CDIM, 1024);
  }

  nonlin_kernel<<<M, 256, 0, stream>>>(q, kv, scale, ff);
  kmean_kernel<<<dim3(128, B), 256, 0, stream>>>(kv, ksum);
  z_kernel<<<M / 4, 256, 0, stream>>>(q, ksum, z);
  kvmat_kernel<<<dim3(32, B * 8), 256, 0, stream>>>(kv, kvm);
  attn_kernel<<<dim3(N_TOK / 64, B * 8), 256, 0, stream>>>(q, kvm, z);
  conv_kernel<<<dim3(8, 8, B * 8 * 2), 256, 0, stream>>>(kv, q, dwc_w, dwc_b);

  if (use_mfma) {
    split_kernel<<<2048, 256, 0, stream>>>(q, xh, xl, M * 512 / 4);   // y -> planes (reuse x planes)
    gemm_s3<<<dim3(M / 128, 4), 256, 0, stream>>>(xh, xl, wph, wpl, bp, (float*)d_out, CDIM, 512);
  } else {
    gemm_nt<<<dim3(M / 128, 4), 256, 0, stream>>>(q, Wp, bp, (float*)d_out, CDIM, 512);
  }
}

// Round 4
// 1516.756 us; speedup vs baseline: 3.2551x; 1.7482x over previous
//
#include <hip/hip_runtime.h>
#include <cstdio>

#define N_TOK 16384
#define CDIM  512

typedef unsigned short ushort_t;
typedef __attribute__((ext_vector_type(8))) __bf16 bf16x8;
typedef __attribute__((ext_vector_type(4))) float f32x4;

// ---------------------------------------------------------------- helpers
__device__ __forceinline__ ushort_t f2bf(float f) {
  union { float f; unsigned u; } v; v.f = f;
  unsigned r = v.u + 0x7FFFu + ((v.u >> 16) & 1u);   // RN-even
  return (ushort_t)(r >> 16);
}
__device__ __forceinline__ float bf2f(ushort_t h) {
  union { unsigned u; float f; } v; v.u = ((unsigned)h) << 16;
  return v.f;
}

// ---------------------------------------------------------------- zero
__global__ void zero_kernel(float* __restrict__ p, int n) {
  int i = blockIdx.x * blockDim.x + threadIdx.x;
  if (i < n) p[i] = 0.f;
}

// ---------------------------------------------------------------- split-bf16 MFMA GEMM, on-the-fly split
// C[M x Nout] = A[M x K] * B[Nout x K]^T + bias  (A,B fp32 in global).
// Per K-step: stage A,B 128x32 fp32 tiles -> hi/lo bf16 LDS planes (2-bit XOR
// chunk swizzle), then 3-pass MFMA: Ah*Bh + Ah*Bl + Al*Bh, fp32 accum.
// grid=(M/128, Nout/128), 256 thr = 4 waves, each wave owns a 64x64 quadrant.
__global__ __launch_bounds__(256, 2) void gemm_s3f(const float* __restrict__ A,
                                                   const float* __restrict__ Bw,
                                                   const float* __restrict__ bias,
                                                   float* __restrict__ C,
                                                   const int K, const int ldc) {
  __shared__ __align__(16) ushort_t Ash[128 * 32];
  __shared__ __align__(16) ushort_t Asl[128 * 32];
  __shared__ __align__(16) ushort_t Bsh[128 * 32];
  __shared__ __align__(16) ushort_t Bsl[128 * 32];
  const int t = threadIdx.x;
  const int lane = t & 63;
  const int w = t >> 6;
  const int wr = w >> 1, wc = w & 1;          // wave quadrant (2x2 of 64x64)
  const size_t bm = (size_t)blockIdx.x * 128;
  const size_t bn = (size_t)blockIdx.y * 128;

  // fragment read offsets: row = base + (lane&15); chunk swizzle (l>>4)^(l&3)
  const int lr  = lane & 15;
  const int lk8 = (((lane >> 4) ^ (lane & 3)) * 8);

  f32x4 acc[4][4] = {};
  float4 fa[4], fb[4];

  // per-thread staging geometry: idx = i*256+t; row = idx>>3; col4 = idx&7
  auto load_tiles = [&](int k0) {
#pragma unroll
    for (int i = 0; i < 4; ++i) {
      const int idx = i * 256 + t;
      const int row = idx >> 3, c4 = idx & 7;
      fa[i] = *(const float4*)(A  + (bm + row) * (size_t)K + k0 + c4 * 4);
      fb[i] = *(const float4*)(Bw + (bn + row) * (size_t)K + k0 + c4 * 4);
    }
  };
  auto store_tiles = [&]() {
#pragma unroll
    for (int i = 0; i < 4; ++i) {
      const int idx = i * 256 + t;
      const int row = idx >> 3, c4 = idx & 7;
      const int off = row * 32 + ((c4 * 4) ^ ((row & 3) * 8));
      ushort4 h, l;
      h.x = f2bf(fa[i].x); l.x = f2bf(fa[i].x - bf2f(h.x));
      h.y = f2bf(fa[i].y); l.y = f2bf(fa[i].y - bf2f(h.y));
      h.z = f2bf(fa[i].z); l.z = f2bf(fa[i].z - bf2f(h.z));
      h.w = f2bf(fa[i].w); l.w = f2bf(fa[i].w - bf2f(h.w));
      *(ushort4*)&Ash[off] = h;
      *(ushort4*)&Asl[off] = l;
      h.x = f2bf(fb[i].x); l.x = f2bf(fb[i].x - bf2f(h.x));
      h.y = f2bf(fb[i].y); l.y = f2bf(fb[i].y - bf2f(h.y));
      h.z = f2bf(fb[i].z); l.z = f2bf(fb[i].z - bf2f(h.z));
      h.w = f2bf(fb[i].w); l.w = f2bf(fb[i].w - bf2f(h.w));
      *(ushort4*)&Bsh[off] = h;
      *(ushort4*)&Bsl[off] = l;
    }
  };

  const int nsteps = K >> 5;
  load_tiles(0);
  for (int s = 0; s < nsteps; ++s) {
    __syncthreads();            // LDS free (prev step's readers done)
    store_tiles();
    __syncthreads();            // LDS ready
    bf16x8 ah[4], al[4], bh[4], bl[4];
#pragma unroll
    for (int i = 0; i < 4; ++i) {
      ah[i] = *(const bf16x8*)&Ash[(wr * 64 + i * 16 + lr) * 32 + lk8];
      al[i] = *(const bf16x8*)&Asl[(wr * 64 + i * 16 + lr) * 32 + lk8];
      bh[i] = *(const bf16x8*)&Bsh[(wc * 64 + i * 16 + lr) * 32 + lk8];
      bl[i] = *(const bf16x8*)&Bsl[(wc * 64 + i * 16 + lr) * 32 + lk8];
    }
    if (s + 1 < nsteps) load_tiles((s + 1) << 5);   // prefetch under MFMA
#pragma unroll
    for (int mi = 0; mi < 4; ++mi)
#pragma unroll
      for (int ni = 0; ni < 4; ++ni) {
        acc[mi][ni] = __builtin_amdgcn_mfma_f32_16x16x32_bf16(ah[mi], bh[ni], acc[mi][ni], 0, 0, 0);
        acc[mi][ni] = __builtin_amdgcn_mfma_f32_16x16x32_bf16(ah[mi], bl[ni], acc[mi][ni], 0, 0, 0);
        acc[mi][ni] = __builtin_amdgcn_mfma_f32_16x16x32_bf16(al[mi], bh[ni], acc[mi][ni], 0, 0, 0);
      }
  }

  // epilogue: C/D layout col=lane&15, row=(lane>>4)*4+reg (m89-verified)
  const int rg = (lane >> 4) << 2;
#pragma unroll
  for (int ni = 0; ni < 4; ++ni) {
    const int col = (int)bn + wc * 64 + ni * 16 + lr;
    const float bs = bias[col];
#pragma unroll
    for (int mi = 0; mi < 4; ++mi) {
      float* Cp = C + (bm + wr * 64 + mi * 16 + rg) * (size_t)ldc + col;
#pragma unroll
      for (int j = 0; j < 4; ++j)
        Cp[(size_t)j * ldc] = acc[mi][ni][j] + bs;
    }
  }
}

// ---------------------------------------------------------------- fp32 fallback GEMM (kept for safety/debug)
__global__ __launch_bounds__(256) void gemm_nt(const float* __restrict__ A,
                                               const float* __restrict__ B,
                                               const float* __restrict__ bias,
                                               float* __restrict__ C,
                                               int K, int ldc) {
  __shared__ float As[16][132];
  __shared__ float Bs[16][132];
  const int t = threadIdx.x;
  const size_t bm = (size_t)blockIdx.x * 128;
  const size_t bn = (size_t)blockIdx.y * 128;
  const int arow = t >> 2;
  const int ak4  = (t & 3) * 4;
  const int tr   = (t >> 4) * 8;
  const int tc   = (t & 15) * 8;
  float acc[8][8] = {};
  const float* Ab = A + (bm + arow) * (size_t)K + ak4;
  const float* Bb = B + (bn + arow) * (size_t)K + ak4;
  for (int k0 = 0; k0 < K; k0 += 16) {
    float4 av0 = *(const float4*)(Ab + k0);
    float4 av1 = *(const float4*)(Ab + (size_t)64 * K + k0);
    float4 bv0 = *(const float4*)(Bb + k0);
    float4 bv1 = *(const float4*)(Bb + (size_t)64 * K + k0);
    __syncthreads();
    As[ak4+0][arow]    = av0.x; As[ak4+1][arow]    = av0.y;
    As[ak4+2][arow]    = av0.z; As[ak4+3][arow]    = av0.w;
    As[ak4+0][arow+64] = av1.x; As[ak4+1][arow+64] = av1.y;
    As[ak4+2][arow+64] = av1.z; As[ak4+3][arow+64] = av1.w;
    Bs[ak4+0][arow]    = bv0.x; Bs[ak4+1][arow]    = bv0.y;
    Bs[ak4+2][arow]    = bv0.z; Bs[ak4+3][arow]    = bv0.w;
    Bs[ak4+0][arow+64] = bv1.x; Bs[ak4+1][arow+64] = bv1.y;
    Bs[ak4+2][arow+64] = bv1.z; Bs[ak4+3][arow+64] = bv1.w;
    __syncthreads();
#pragma unroll
    for (int kk = 0; kk < 16; ++kk) {
      float a[8], b[8];
      *(float4*)&a[0] = *(const float4*)&As[kk][tr];
      *(float4*)&a[4] = *(const float4*)&As[kk][tr + 4];
      *(float4*)&b[0] = *(const float4*)&Bs[kk][tc];
      *(float4*)&b[4] = *(const float4*)&Bs[kk][tc + 4];
#pragma unroll
      for (int i = 0; i < 8; ++i)
#pragma unroll
        for (int j = 0; j < 8; ++j)
          acc[i][j] = fmaf(a[i], b[j], acc[i][j]);
    }
  }
#pragma unroll
  for (int i = 0; i < 8; ++i) {
    float o[8];
#pragma unroll
    for (int j = 0; j < 8; ++j) o[j] = acc[i][j] + bias[bn + tc + j];
    float* Cr = C + (bm + tr + i) * (size_t)ldc + bn + tc;
    *(float4*)&Cr[0] = *(float4*)&o[0];
    *(float4*)&Cr[4] = *(float4*)&o[4];
  }
}

// ---------------------------------------------------------------- nonlinearity
__global__ __launch_bounds__(256) void nonlin_kernel(float* __restrict__ q,
                                                     float* __restrict__ kv,
                                                     const float* __restrict__ scale,
                                                     const float* __restrict__ ff) {
  __shared__ float red[8];
  const int row = blockIdx.x;
  const int t = threadIdx.x;
  const int wid = t >> 6, lane = t & 63;
  float* qr = q + (size_t)row * 512;
  float* kr = kv + (size_t)row * 1024;

  float sc0 = scale[t], sc1 = scale[t + 256];
  float s0 = (sc0 > 20.f) ? sc0 : log1pf(expf(sc0));
  float s1 = (sc1 > 20.f) ? sc1 : log1pf(expf(sc1));
  float f0 = ff[t], f1 = ff[t + 256];

  float q0 = (fmaxf(qr[t], 0.f) + 1e-6f) / s0;
  float q1 = (fmaxf(qr[t + 256], 0.f) + 1e-6f) / s1;
  float k0 = (fmaxf(kr[t], 0.f) + 1e-6f) / s0;
  float k1 = (fmaxf(kr[t + 256], 0.f) + 1e-6f) / s1;

  float sq = q0 * q0 + q1 * q1;
  float sk = k0 * k0 + k1 * k1;
  for (int off = 32; off > 0; off >>= 1) {
    sq += __shfl_down(sq, off);
    sk += __shfl_down(sk, off);
  }
  if (lane == 0) { red[wid * 2] = sq; red[wid * 2 + 1] = sk; }
  __syncthreads();
  float qn = sqrtf(red[0] + red[2] + red[4] + red[6]);
  float kn = sqrtf(red[1] + red[3] + red[5] + red[7]);
  __syncthreads();

  float pq0 = powf(q0, f0), pq1 = powf(q1, f1);
  float pk0 = powf(k0, f0), pk1 = powf(k1, f1);

  float sq2 = pq0 * pq0 + pq1 * pq1;
  float sk2 = pk0 * pk0 + pk1 * pk1;
  for (int off = 32; off > 0; off >>= 1) {
    sq2 += __shfl_down(sq2, off);
    sk2 += __shfl_down(sk2, off);
  }
  if (lane == 0) { red[wid * 2] = sq2; red[wid * 2 + 1] = sk2; }
  __syncthreads();
  float pqn = sqrtf(red[0] + red[2] + red[4] + red[6]);
  float pkn = sqrtf(red[1] + red[3] + red[5] + red[7]);

  float qs = qn / pqn, ks = kn / pkn;
  qr[t] = pq0 * qs;
  qr[t + 256] = pq1 * qs;
  kr[t] = pk0 * ks;
  kr[t + 256] = pk1 * ks;
}

// ---------------------------------------------------------------- k sum over N
__global__ __launch_bounds__(256) void kmean_kernel(const float* __restrict__ kv,
                                                    float* __restrict__ ksum) {
  const int b = blockIdx.y, ch = blockIdx.x, t = threadIdx.x;
  size_t base = ((size_t)b * N_TOK + (size_t)ch * 128) * 1024;
  float a0 = 0.f, a1 = 0.f;
  for (int i = 0; i < 128; ++i) {
    const float* r = kv + base + (size_t)i * 1024;
    a0 += r[t];
    a1 += r[t + 256];
  }
  atomicAdd(&ksum[b * 512 + t], a0);
  atomicAdd(&ksum[b * 512 + t + 256], a1);
}

// ---------------------------------------------------------------- z = 1/(q . k_mean + eps)
__global__ __launch_bounds__(256) void z_kernel(const float* __restrict__ q,
                                                const float* __restrict__ ksum,
                                                float* __restrict__ z) {
  const int t = threadIdx.x;
  const int w = t >> 6, lane = t & 63;
  const int row = blockIdx.x * 4 + w;
  const int b = row >> 14, n = row & (N_TOK - 1);
  const int hh = lane >> 3, j = lane & 7;
  const float* qr = q + (size_t)row * 512 + hh * 64 + j * 8;
  const float* kr = ksum + b * 512 + hh * 64 + j * 8;
  float p = 0.f;
#pragma unroll
  for (int i = 0; i < 8; ++i) p += qr[i] * kr[i];
  p += __shfl_xor(p, 1);
  p += __shfl_xor(p, 2);
  p += __shfl_xor(p, 4);
  if (j == 0) {
    float dot = p * (1.0f / (float)N_TOK);
    z[((size_t)(b * 8 + hh)) * N_TOK + n] = 1.0f / (dot + 1e-6f);
  }
}

// ---------------------------------------------------------------- kv_mat[bh] = k^T v / N
__global__ __launch_bounds__(256) void kvmat_kernel(const float* __restrict__ kv,
                                                    float* __restrict__ kvm) {
  __shared__ float ks[8][64];
  __shared__ float vs[8][64];
  const int bh = blockIdx.y;
  const int b = bh >> 3, h = bh & 7;
  const int chunk = blockIdx.x;
  const int t = threadIdx.x;
  const int tr = (t >> 4) * 4, tc = (t & 15) * 4;
  float acc[4][4] = {};
  size_t rowbase = (size_t)b * N_TOK + (size_t)chunk * 512;
  for (int it = 0; it < 64; ++it) {
    __syncthreads();
#pragma unroll
    for (int l = 0; l < 4; ++l) {
      int idx = l * 256 + t;
      int ri = idx >> 7, ci = idx & 127;
      size_t g = (rowbase + it * 8 + ri) * 1024 + h * 64;
      if (ci < 64) ks[ri][ci] = kv[g + ci];
      else         vs[ri][ci - 64] = kv[g + 512 + (ci - 64)];
    }
    __syncthreads();
#pragma unroll
    for (int ri = 0; ri < 8; ++ri) {
      float a[4], v4[4];
#pragma unroll
      for (int i = 0; i < 4; ++i) a[i] = ks[ri][tr + i];
#pragma unroll
      for (int j = 0; j < 4; ++j) v4[j] = vs[ri][tc + j];
#pragma unroll
      for (int i = 0; i < 4; ++i)
#pragma unroll
        for (int j = 0; j < 4; ++j)
          acc[i][j] = fmaf(a[i], v4[j], acc[i][j]);
    }
  }
  const float scl = 1.0f / (float)N_TOK;
#pragma unroll
  for (int i = 0; i < 4; ++i)
#pragma unroll
    for (int j = 0; j < 4; ++j)
      atomicAdd(&kvm[(size_t)bh * 4096 + (tr + i) * 64 + (tc + j)], acc[i][j] * scl);
}

// ---------------------------------------------------------------- attn: q <- (q @ kvm) * z
__global__ __launch_bounds__(256) void attn_kernel(float* __restrict__ q,
                                                   const float* __restrict__ kvm,
                                                   const float* __restrict__ z) {
  __shared__ float km[64][64];
  __shared__ float qs[64][64];
  const int bh = blockIdx.y;
  const int b = bh >> 3, h = bh & 7;
  const int tok0 = blockIdx.x * 64;
  const int t = threadIdx.x;
  const size_t kvm_base = (size_t)bh * 4096;
  const size_t qbase = ((size_t)b * N_TOK + tok0) * 512 + h * 64;
#pragma unroll
  for (int i = 0; i < 16; ++i) {
    int idx = i * 256 + t;
    km[idx >> 6][idx & 63] = kvm[kvm_base + idx];
    qs[idx >> 6][idx & 63] = q[qbase + (size_t)(idx >> 6) * 512 + (idx & 63)];
  }
  __syncthreads();
  const int d = t & 63, slot = t >> 6;
  const float* zrow = z + (size_t)bh * N_TOK + tok0;
  for (int i = 0; i < 16; ++i) {
    const int tok = i * 4 + slot;
    float a0 = 0.f, a1 = 0.f, a2 = 0.f, a3 = 0.f;
#pragma unroll
    for (int din = 0; din < 64; din += 4) {
      a0 = fmaf(qs[tok][din + 0], km[din + 0][d], a0);
      a1 = fmaf(qs[tok][din + 1], km[din + 1][d], a1);
      a2 = fmaf(qs[tok][din + 2], km[din + 2][d], a2);
      a3 = fmaf(qs[tok][din + 3], km[din + 3][d], a3);
    }
    q[qbase + (size_t)tok * 512 + d] = ((a0 + a1) + (a2 + a3)) * zrow[tok];
  }
}

// ---------------------------------------------------------------- depthwise 5x5 conv on v, += into y
__global__ __launch_bounds__(256) void conv_kernel(const float* __restrict__ kv,
                                                   float* __restrict__ y,
                                                   const float* __restrict__ wconv,
                                                   const float* __restrict__ bconv) {
  __shared__ float vt[20 * 20 * 32];
  const int zidx = blockIdx.z;
  const int bh = zidx >> 1, chalf = zidx & 1;
  const int b = bh >> 3, h = bh & 7;
  const int c0 = chalf * 32;
  const int tx0 = blockIdx.x * 16, ty0 = blockIdx.y * 16;
  const int t = threadIdx.x;
  const int c = t & 31;
  const size_t vbase = (size_t)b * N_TOK * 1024 + 512 + h * 64 + c0 + c;
  for (int i = 0; i < 50; ++i) {
    int idx = i * 256 + t;
    int pix = idx >> 5;
    int lx = pix % 20, ly = pix / 20;
    int gx = tx0 + lx - 2, gy = ty0 + ly - 2;
    float val = 0.f;
    if ((unsigned)gx < 128u && (unsigned)gy < 128u)
      val = kv[vbase + ((size_t)(gy * 128 + gx)) * 1024 - (size_t)c + (size_t)(idx & 31)];
    vt[pix * 32 + (idx & 31)] = val;
  }
  const int dd = c0 + c;
  float w[25];
#pragma unroll
  for (int k = 0; k < 25; ++k) w[k] = wconv[dd * 25 + k];
  const float bb = bconv[dd];
  __syncthreads();
  const int slot = t >> 5;
  for (int i = 0; i < 32; ++i) {
    const int pix = i * 8 + slot;
    const int px = pix & 15, py = pix >> 4;
    float acc = bb;
#pragma unroll
    for (int ky = 0; ky < 5; ++ky)
#pragma unroll
      for (int kx = 0; kx < 5; ++kx)
        acc = fmaf(w[ky * 5 + kx], vt[((py + ky) * 20 + (px + kx)) * 32 + c], acc);
    size_t o = ((size_t)b * N_TOK + (size_t)(ty0 + py) * 128 + (tx0 + px)) * 512 + h * 64 + dd;
    y[o] += acc;
  }
}

// ---------------------------------------------------------------- launch
extern "C" void kernel_launch(void* const* d_in, const int* in_sizes, int n_in,
                              void* d_out, int out_size, void* d_ws, size_t ws_size,
                              hipStream_t stream) {
  (void)n_in; (void)out_size;
  const float* x     = (const float*)d_in[0];
  const float* Wq    = (const float*)d_in[1];
  const float* bq    = (const float*)d_in[2];
  const float* Wkv   = (const float*)d_in[3];
  const float* bkv   = (const float*)d_in[4];
  const float* Wp    = (const float*)d_in[5];
  const float* bp    = (const float*)d_in[6];
  const float* ff    = (const float*)d_in[7];
  const float* scale = (const float*)d_in[8];
  const float* dwc_w = (const float*)d_in[9];
  const float* dwc_b = (const float*)d_in[10];

  const int B = in_sizes[0] / (N_TOK * CDIM);   // 4
  const int M = B * N_TOK;                      // 65536

  // workspace layout: identical to the round-1 known-good 405.3 MB footprint
  float* q    = (float*)d_ws;                          // M x 512
  float* kv   = q + (size_t)M * 512;                   // M x 1024 (k | v)
  float* ksum = kv + (size_t)M * 1024;                 // B x 512
  float* kvm  = ksum + (size_t)B * 512;                // 32 x 64 x 64
  float* z    = kvm + (size_t)B * 8 * 4096;            // 32 x N

  size_t need = ((size_t)M * 1536 + (size_t)B * 512 + (size_t)B * 8 * 4096 +
                 (size_t)B * 8 * N_TOK) * sizeof(float);
  if (ws_size < need) {
    fprintf(stderr, "kernel_launch: ws too small (%zu < %zu)\n", ws_size, need);
    return;
  }

  const int nsmall = B * 512 + B * 8 * 4096;
  zero_kernel<<<(nsmall + 255) / 256, 256, 0, stream>>>(ksum, nsmall);

  gemm_s3f<<<dim3(M / 128, 4), 256, 0, stream>>>(x, Wq, bq, q, CDIM, 512);
  gemm_s3f<<<dim3(M / 128, 8), 256, 0, stream>>>(x, Wkv, bkv, kv, CDIM, 1024);

  nonlin_kernel<<<M, 256, 0, stream>>>(q, kv, scale, ff);
  kmean_kernel<<<dim3(128, B), 256, 0, stream>>>(kv, ksum);
  z_kernel<<<M / 4, 256, 0, stream>>>(q, ksum, z);
  kvmat_kernel<<<dim3(32, B * 8), 256, 0, stream>>>(kv, kvm);
  attn_kernel<<<dim3(N_TOK / 64, B * 8), 256, 0, stream>>>(q, kvm, z);
  conv_kernel<<<dim3(8, 8, B * 8 * 2), 256, 0, stream>>>(kv, q, dwc_w, dwc_b);

  gemm_s3f<<<dim3(M / 128, 4), 256, 0, stream>>>(q, Wp, bp, (float*)d_out, CDIM, 512);
}

// Round 5
// 1212.016 us; speedup vs baseline: 4.0736x; 1.2514x over previous
//
#include <hip/hip_runtime.h>
#include <cstdio>

#define N_TOK 16384
#define CDIM  512

typedef unsigned short ushort_t;
typedef __attribute__((ext_vector_type(8))) __bf16 bf16x8;
typedef __attribute__((ext_vector_type(4))) float f32x4;

// ---------------------------------------------------------------- helpers
__device__ __forceinline__ ushort_t f2bf(float f) {
  union { float f; unsigned u; } v; v.f = f;
  unsigned r = v.u + 0x7FFFu + ((v.u >> 16) & 1u);   // RN-even
  return (ushort_t)(r >> 16);
}
__device__ __forceinline__ float bf2f(ushort_t h) {
  union { unsigned u; float f; } v; v.u = ((unsigned)h) << 16;
  return v.f;
}
// x > 0 guaranteed (relu + 1e-6): x^p = 2^(p*log2(x)) on the HW trans pipe.
__device__ __forceinline__ float fast_pow(float x, float p) {
  return __builtin_amdgcn_exp2f(p * __builtin_amdgcn_logf(x));
}

// ---------------------------------------------------------------- zero
__global__ void zero_kernel(float* __restrict__ p, int n) {
  int i = blockIdx.x * blockDim.x + threadIdx.x;
  if (i < n) p[i] = 0.f;
}

// ---------------------------------------------------------------- 1/softplus(scale), 512 values
__global__ void sp_kernel(const float* __restrict__ scale, float* __restrict__ inv_s) {
  int i = blockIdx.x * blockDim.x + threadIdx.x;
  if (i < 512) {
    float sc = scale[i];
    float s = (sc > 20.f) ? sc : log1pf(expf(sc));
    inv_s[i] = 1.0f / s;
  }
}

// ---------------------------------------------------------------- split-bf16 MFMA GEMM, on-the-fly split
// C[M x Nout] = A[M x K] * B[Nout x K]^T + bias  (A,B fp32 in global).
// Per K-step: stage A,B 128x32 fp32 tiles -> hi/lo bf16 LDS planes (2-bit XOR
// chunk swizzle), then 3-pass MFMA: Ah*Bh + Ah*Bl + Al*Bh, fp32 accum.
__global__ __launch_bounds__(256, 2) void gemm_s3f(const float* __restrict__ A,
                                                   const float* __restrict__ Bw,
                                                   const float* __restrict__ bias,
                                                   float* __restrict__ C,
                                                   const int K, const int ldc) {
  __shared__ __align__(16) ushort_t Ash[128 * 32];
  __shared__ __align__(16) ushort_t Asl[128 * 32];
  __shared__ __align__(16) ushort_t Bsh[128 * 32];
  __shared__ __align__(16) ushort_t Bsl[128 * 32];
  const int t = threadIdx.x;
  const int lane = t & 63;
  const int w = t >> 6;
  const int wr = w >> 1, wc = w & 1;
  const size_t bm = (size_t)blockIdx.x * 128;
  const size_t bn = (size_t)blockIdx.y * 128;

  const int lr  = lane & 15;
  const int lk8 = (((lane >> 4) ^ (lane & 3)) * 8);

  f32x4 acc[4][4] = {};
  float4 fa[4], fb[4];

  auto load_tiles = [&](int k0) {
#pragma unroll
    for (int i = 0; i < 4; ++i) {
      const int idx = i * 256 + t;
      const int row = idx >> 3, c4 = idx & 7;
      fa[i] = *(const float4*)(A  + (bm + row) * (size_t)K + k0 + c4 * 4);
      fb[i] = *(const float4*)(Bw + (bn + row) * (size_t)K + k0 + c4 * 4);
    }
  };
  auto store_tiles = [&]() {
#pragma unroll
    for (int i = 0; i < 4; ++i) {
      const int idx = i * 256 + t;
      const int row = idx >> 3, c4 = idx & 7;
      const int off = row * 32 + ((c4 * 4) ^ ((row & 3) * 8));
      ushort4 h, l;
      h.x = f2bf(fa[i].x); l.x = f2bf(fa[i].x - bf2f(h.x));
      h.y = f2bf(fa[i].y); l.y = f2bf(fa[i].y - bf2f(h.y));
      h.z = f2bf(fa[i].z); l.z = f2bf(fa[i].z - bf2f(h.z));
      h.w = f2bf(fa[i].w); l.w = f2bf(fa[i].w - bf2f(h.w));
      *(ushort4*)&Ash[off] = h;
      *(ushort4*)&Asl[off] = l;
      h.x = f2bf(fb[i].x); l.x = f2bf(fb[i].x - bf2f(h.x));
      h.y = f2bf(fb[i].y); l.y = f2bf(fb[i].y - bf2f(h.y));
      h.z = f2bf(fb[i].z); l.z = f2bf(fb[i].z - bf2f(h.z));
      h.w = f2bf(fb[i].w); l.w = f2bf(fb[i].w - bf2f(h.w));
      *(ushort4*)&Bsh[off] = h;
      *(ushort4*)&Bsl[off] = l;
    }
  };

  const int nsteps = K >> 5;
  load_tiles(0);
  for (int s = 0; s < nsteps; ++s) {
    __syncthreads();
    store_tiles();
    __syncthreads();
    bf16x8 ah[4], al[4], bh[4], bl[4];
#pragma unroll
    for (int i = 0; i < 4; ++i) {
      ah[i] = *(const bf16x8*)&Ash[(wr * 64 + i * 16 + lr) * 32 + lk8];
      al[i] = *(const bf16x8*)&Asl[(wr * 64 + i * 16 + lr) * 32 + lk8];
      bh[i] = *(const bf16x8*)&Bsh[(wc * 64 + i * 16 + lr) * 32 + lk8];
      bl[i] = *(const bf16x8*)&Bsl[(wc * 64 + i * 16 + lr) * 32 + lk8];
    }
    if (s + 1 < nsteps) load_tiles((s + 1) << 5);
#pragma unroll
    for (int mi = 0; mi < 4; ++mi)
#pragma unroll
      for (int ni = 0; ni < 4; ++ni) {
        acc[mi][ni] = __builtin_amdgcn_mfma_f32_16x16x32_bf16(ah[mi], bh[ni], acc[mi][ni], 0, 0, 0);
        acc[mi][ni] = __builtin_amdgcn_mfma_f32_16x16x32_bf16(ah[mi], bl[ni], acc[mi][ni], 0, 0, 0);
        acc[mi][ni] = __builtin_amdgcn_mfma_f32_16x16x32_bf16(al[mi], bh[ni], acc[mi][ni], 0, 0, 0);
      }
  }

  const int rg = (lane >> 4) << 2;
#pragma unroll
  for (int ni = 0; ni < 4; ++ni) {
    const int col = (int)bn + wc * 64 + ni * 16 + lr;
    const float bs = bias[col];
#pragma unroll
    for (int mi = 0; mi < 4; ++mi) {
      float* Cp = C + (bm + wr * 64 + mi * 16 + rg) * (size_t)ldc + col;
#pragma unroll
      for (int j = 0; j < 4; ++j)
        Cp[(size_t)j * ldc] = acc[mi][ni][j] + bs;
    }
  }
}

// ---------------------------------------------------------------- nonlinearity (fast pow, precomputed 1/softplus)
__global__ __launch_bounds__(256) void nonlin_kernel(float* __restrict__ q,
                                                     float* __restrict__ kv,
                                                     const float* __restrict__ inv_s,
                                                     const float* __restrict__ ff) {
  __shared__ float red[8];
  const int row = blockIdx.x;
  const int t = threadIdx.x;
  const int wid = t >> 6, lane = t & 63;
  float* qr = q + (size_t)row * 512;
  float* kr = kv + (size_t)row * 1024;

  float is0 = inv_s[t], is1 = inv_s[t + 256];
  float f0 = ff[t], f1 = ff[t + 256];

  float q0 = (fmaxf(qr[t], 0.f) + 1e-6f) * is0;
  float q1 = (fmaxf(qr[t + 256], 0.f) + 1e-6f) * is1;
  float k0 = (fmaxf(kr[t], 0.f) + 1e-6f) * is0;
  float k1 = (fmaxf(kr[t + 256], 0.f) + 1e-6f) * is1;

  float sq = q0 * q0 + q1 * q1;
  float sk = k0 * k0 + k1 * k1;
  for (int off = 32; off > 0; off >>= 1) {
    sq += __shfl_down(sq, off);
    sk += __shfl_down(sk, off);
  }
  if (lane == 0) { red[wid * 2] = sq; red[wid * 2 + 1] = sk; }
  __syncthreads();
  float qn = sqrtf(red[0] + red[2] + red[4] + red[6]);
  float kn = sqrtf(red[1] + red[3] + red[5] + red[7]);
  __syncthreads();

  float pq0 = fast_pow(q0, f0), pq1 = fast_pow(q1, f1);
  float pk0 = fast_pow(k0, f0), pk1 = fast_pow(k1, f1);

  float sq2 = pq0 * pq0 + pq1 * pq1;
  float sk2 = pk0 * pk0 + pk1 * pk1;
  for (int off = 32; off > 0; off >>= 1) {
    sq2 += __shfl_down(sq2, off);
    sk2 += __shfl_down(sk2, off);
  }
  if (lane == 0) { red[wid * 2] = sq2; red[wid * 2 + 1] = sk2; }
  __syncthreads();
  float pqn = sqrtf(red[0] + red[2] + red[4] + red[6]);
  float pkn = sqrtf(red[1] + red[3] + red[5] + red[7]);

  float qs = qn / pqn, ks = kn / pkn;
  qr[t] = pq0 * qs;
  qr[t + 256] = pq1 * qs;
  kr[t] = pk0 * ks;
  kr[t + 256] = pk1 * ks;
}

// ---------------------------------------------------------------- k sum over N
__global__ __launch_bounds__(256) void kmean_kernel(const float* __restrict__ kv,
                                                    float* __restrict__ ksum) {
  const int b = blockIdx.y, ch = blockIdx.x, t = threadIdx.x;
  size_t base = ((size_t)b * N_TOK + (size_t)ch * 128) * 1024;
  float a0 = 0.f, a1 = 0.f;
  for (int i = 0; i < 128; ++i) {
    const float* r = kv + base + (size_t)i * 1024;
    a0 += r[t];
    a1 += r[t + 256];
  }
  atomicAdd(&ksum[b * 512 + t], a0);
  atomicAdd(&ksum[b * 512 + t + 256], a1);
}

// ---------------------------------------------------------------- z = 1/(q . k_mean + eps)
__global__ __launch_bounds__(256) void z_kernel(const float* __restrict__ q,
                                                const float* __restrict__ ksum,
                                                float* __restrict__ z) {
  const int t = threadIdx.x;
  const int w = t >> 6, lane = t & 63;
  const int row = blockIdx.x * 4 + w;
  const int b = row >> 14, n = row & (N_TOK - 1);
  const int hh = lane >> 3, j = lane & 7;
  const float* qr = q + (size_t)row * 512 + hh * 64 + j * 8;
  const float* kr = ksum + b * 512 + hh * 64 + j * 8;
  float p = 0.f;
#pragma unroll
  for (int i = 0; i < 8; ++i) p += qr[i] * kr[i];
  p += __shfl_xor(p, 1);
  p += __shfl_xor(p, 2);
  p += __shfl_xor(p, 4);
  if (j == 0) {
    float dot = p * (1.0f / (float)N_TOK);
    z[((size_t)(b * 8 + hh)) * N_TOK + n] = 1.0f / (dot + 1e-6f);
  }
}

// ---------------------------------------------------------------- kv_mat[bh] = k^T v / N
__global__ __launch_bounds__(256) void kvmat_kernel(const float* __restrict__ kv,
                                                    float* __restrict__ kvm) {
  __shared__ float ks[8][64];
  __shared__ float vs[8][64];
  const int bh = blockIdx.y;
  const int b = bh >> 3, h = bh & 7;
  const int chunk = blockIdx.x;
  const int t = threadIdx.x;
  const int tr = (t >> 4) * 4, tc = (t & 15) * 4;
  float acc[4][4] = {};
  size_t rowbase = (size_t)b * N_TOK + (size_t)chunk * 512;
  for (int it = 0; it < 64; ++it) {
    __syncthreads();
#pragma unroll
    for (int l = 0; l < 4; ++l) {
      int idx = l * 256 + t;
      int ri = idx >> 7, ci = idx & 127;
      size_t g = (rowbase + it * 8 + ri) * 1024 + h * 64;
      if (ci < 64) ks[ri][ci] = kv[g + ci];
      else         vs[ri][ci - 64] = kv[g + 512 + (ci - 64)];
    }
    __syncthreads();
#pragma unroll
    for (int ri = 0; ri < 8; ++ri) {
      float a[4], v4[4];
#pragma unroll
      for (int i = 0; i < 4; ++i) a[i] = ks[ri][tr + i];
#pragma unroll
      for (int j = 0; j < 4; ++j) v4[j] = vs[ri][tc + j];
#pragma unroll
      for (int i = 0; i < 4; ++i)
#pragma unroll
        for (int j = 0; j < 4; ++j)
          acc[i][j] = fmaf(a[i], v4[j], acc[i][j]);
    }
  }
  const float scl = 1.0f / (float)N_TOK;
#pragma unroll
  for (int i = 0; i < 4; ++i)
#pragma unroll
    for (int j = 0; j < 4; ++j)
      atomicAdd(&kvm[(size_t)bh * 4096 + (tr + i) * 64 + (tc + j)], acc[i][j] * scl);
}

// ---------------------------------------------------------------- attn: q <- (q @ kvm) * z
__global__ __launch_bounds__(256) void attn_kernel(float* __restrict__ q,
                                                   const float* __restrict__ kvm,
                                                   const float* __restrict__ z) {
  __shared__ float km[64][64];
  __shared__ float qs[64][64];
  const int bh = blockIdx.y;
  const int b = bh >> 3, h = bh & 7;
  const int tok0 = blockIdx.x * 64;
  const int t = threadIdx.x;
  const size_t kvm_base = (size_t)bh * 4096;
  const size_t qbase = ((size_t)b * N_TOK + tok0) * 512 + h * 64;
#pragma unroll
  for (int i = 0; i < 16; ++i) {
    int idx = i * 256 + t;
    km[idx >> 6][idx & 63] = kvm[kvm_base + idx];
    qs[idx >> 6][idx & 63] = q[qbase + (size_t)(idx >> 6) * 512 + (idx & 63)];
  }
  __syncthreads();
  const int d = t & 63, slot = t >> 6;
  const float* zrow = z + (size_t)bh * N_TOK + tok0;
  for (int i = 0; i < 16; ++i) {
    const int tok = i * 4 + slot;
    float a0 = 0.f, a1 = 0.f, a2 = 0.f, a3 = 0.f;
#pragma unroll
    for (int din = 0; din < 64; din += 4) {
      a0 = fmaf(qs[tok][din + 0], km[din + 0][d], a0);
      a1 = fmaf(qs[tok][din + 1], km[din + 1][d], a1);
      a2 = fmaf(qs[tok][din + 2], km[din + 2][d], a2);
      a3 = fmaf(qs[tok][din + 3], km[din + 3][d], a3);
    }
    q[qbase + (size_t)tok * 512 + d] = ((a0 + a1) + (a2 + a3)) * zrow[tok];
  }
}

// ---------------------------------------------------------------- depthwise 5x5 conv on v, += into y
__global__ __launch_bounds__(256) void conv_kernel(const float* __restrict__ kv,
                                                   float* __restrict__ y,
                                                   const float* __restrict__ wconv,
                                                   const float* __restrict__ bconv) {
  __shared__ float vt[20 * 20 * 32];
  const int zidx = blockIdx.z;
  const int bh = zidx >> 1, chalf = zidx & 1;
  const int b = bh >> 3, h = bh & 7;
  const int c0 = chalf * 32;
  const int tx0 = blockIdx.x * 16, ty0 = blockIdx.y * 16;
  const int t = threadIdx.x;
  const int c = t & 31;
  const size_t vbase = (size_t)b * N_TOK * 1024 + 512 + h * 64 + c0 + c;
  for (int i = 0; i < 50; ++i) {
    int idx = i * 256 + t;
    int pix = idx >> 5;
    int lx = pix % 20, ly = pix / 20;
    int gx = tx0 + lx - 2, gy = ty0 + ly - 2;
    float val = 0.f;
    if ((unsigned)gx < 128u && (unsigned)gy < 128u)
      val = kv[vbase + ((size_t)(gy * 128 + gx)) * 1024 - (size_t)c + (size_t)(idx & 31)];
    vt[pix * 32 + (idx & 31)] = val;
  }
  const int dd = c0 + c;
  float w[25];
#pragma unroll
  for (int k = 0; k < 25; ++k) w[k] = wconv[dd * 25 + k];
  const float bb = bconv[dd];
  __syncthreads();
  const int slot = t >> 5;
  for (int i = 0; i < 32; ++i) {
    const int pix = i * 8 + slot;
    const int px = pix & 15, py = pix >> 4;
    float acc = bb;
#pragma unroll
    for (int ky = 0; ky < 5; ++ky)
#pragma unroll
      for (int kx = 0; kx < 5; ++kx)
        acc = fmaf(w[ky * 5 + kx], vt[((py + ky) * 20 + (px + kx)) * 32 + c], acc);
    size_t o = ((size_t)b * N_TOK + (size_t)(ty0 + py) * 128 + (tx0 + px)) * 512 + h * 64 + dd;
    y[o] += acc;
  }
}

// ---------------------------------------------------------------- launch
extern "C" void kernel_launch(void* const* d_in, const int* in_sizes, int n_in,
                              void* d_out, int out_size, void* d_ws, size_t ws_size,
                              hipStream_t stream) {
  (void)n_in; (void)out_size;
  const float* x     = (const float*)d_in[0];
  const float* Wq    = (const float*)d_in[1];
  const float* bq    = (const float*)d_in[2];
  const float* Wkv   = (const float*)d_in[3];
  const float* bkv   = (const float*)d_in[4];
  const float* Wp    = (const float*)d_in[5];
  const float* bp    = (const float*)d_in[6];
  const float* ff    = (const float*)d_in[7];
  const float* scale = (const float*)d_in[8];
  const float* dwc_w = (const float*)d_in[9];
  const float* dwc_b = (const float*)d_in[10];

  const int B = in_sizes[0] / (N_TOK * CDIM);   // 4
  const int M = B * N_TOK;                      // 65536

  // workspace layout: identical to the round-1 known-good 405.3 MB footprint
  float* q    = (float*)d_ws;                          // M x 512
  float* kv   = q + (size_t)M * 512;                   // M x 1024 (k | v)
  float* ksum = kv + (size_t)M * 1024;                 // B x 512
  float* kvm  = ksum + (size_t)B * 512;                // 32 x 64 x 64
  float* z    = kvm + (size_t)B * 8 * 4096;            // 32 x N

  size_t need = ((size_t)M * 1536 + (size_t)B * 512 + (size_t)B * 8 * 4096 +
                 (size_t)B * 8 * N_TOK) * sizeof(float);
  if (ws_size < need) {
    fprintf(stderr, "kernel_launch: ws too small (%zu < %zu)\n", ws_size, need);
    return;
  }

  // inv_s lives in the head of z: consumed by nonlin BEFORE z_kernel
  // overwrites the z buffer. Recomputed every launch (deterministic).
  float* inv_s = z;

  const int nsmall = B * 512 + B * 8 * 4096;
  zero_kernel<<<(nsmall + 255) / 256, 256, 0, stream>>>(ksum, nsmall);
  sp_kernel<<<2, 256, 0, stream>>>(scale, inv_s);

  gemm_s3f<<<dim3(M / 128, 4), 256, 0, stream>>>(x, Wq, bq, q, CDIM, 512);
  gemm_s3f<<<dim3(M / 128, 8), 256, 0, stream>>>(x, Wkv, bkv, kv, CDIM, 1024);

  nonlin_kernel<<<M, 256, 0, stream>>>(q, kv, inv_s, ff);
  kmean_kernel<<<dim3(128, B), 256, 0, stream>>>(kv, ksum);
  z_kernel<<<M / 4, 256, 0, stream>>>(q, ksum, z);
  kvmat_kernel<<<dim3(32, B * 8), 256, 0, stream>>>(kv, kvm);
  attn_kernel<<<dim3(N_TOK / 64, B * 8), 256, 0, stream>>>(q, kvm, z);
  conv_kernel<<<dim3(8, 8, B * 8 * 2), 256, 0, stream>>>(kv, q, dwc_w, dwc_b);

  gemm_s3f<<<dim3(M / 128, 4), 256, 0, stream>>>(q, Wp, bp, (float*)d_out, CDIM, 512);
}